// Round 3
// 675.998 us; speedup vs baseline: 1.0748x; 1.0748x over previous
//
#include <hip/hip_runtime.h>
#include <cstddef>

#define CC   128
#define LDIM 361
#define MDIM 361
#define KDIM 361
#define NLON 720
#define LP   384          // padded l (stage A K-dim)
#define KP   384          // padded k rows for pctT
#define MRP  736          // padded mr (stage B K-dim)
#define NP   768          // padded n (stage B N-dim)
#define CK   (CC*KDIM)    // 46208
#define CR   (2*CC)       // 256

typedef __attribute__((ext_vector_type(8))) short short8;
typedef __attribute__((ext_vector_type(4))) float floatx4;

__device__ __forceinline__ unsigned short f2bf(float f) {
    union { float f; unsigned u; } v; v.f = f;
    unsigned u = v.u;
    u += 0x7fffu + ((u >> 16) & 1u);   // RNE
    return (unsigned short)(u >> 16);
}

__device__ __forceinline__ void async_copy16(const void* g, void* l) {
    __builtin_amdgcn_global_load_lds(
        (const __attribute__((address_space(1))) void*)g,
        (__attribute__((address_space(3))) void*)l, 16, 0, 0);
}

// Bijective XCD-chunk swizzle (m204).
__device__ __forceinline__ int xcd_swz(int id, int P) {
    int x = id & 7, g = id >> 3;
    int q = P >> 3, r = P & 7;
    int start = (x < r) ? x * (q + 1) : r * (q + 1) + (x - r) * q;
    return start + g;
}

// ---------------------------------------------------------------------------
// Tp[n][mr] bf16, n<720 & mr<722 real weights, else 0 (pad kills xs poison).
__global__ void sht_gen_T(unsigned short* __restrict__ Tp) {
    int idx = blockIdx.x * 256 + threadIdx.x;
    if (idx >= NP * MRP) return;
    int n = idx / MRP, mr = idx - n * MRP;
    float v = 0.f;
    if (n < NLON && mr < 2 * MDIM) {
        int m = mr >> 1, im = mr & 1;
        if (m == 0)            v = im ? 0.f : 1.f;
        else if (m == MDIM-1)  v = im ? 0.f : ((n & 1) ? -1.f : 1.f);
        else {
            int ph = (m * n) % NLON;
            float ang = (float)ph * (float)(3.14159265358979323846 / 360.0);
            v = im ? (-2.f * sinf(ang)) : (2.f * cosf(ang));
        }
    }
    Tp[idx] = f2bf(v);
}

// ---------------------------------------------------------------------------
// x fp32 [c][l][m][r] -> xA bf16 [m][cr=2c+r][LP]  (l-fast, zero pad l>=361)
// Two f32 planes: read phase touches only the needed plane; <=2-way aliasing.
__global__ __launch_bounds__(256)
void sht_prep_x(const float* __restrict__ x, unsigned short* __restrict__ xA) {
    __shared__ float tp[2][64 * 33 + 4];
    const int mt = blockIdx.x;         // 0..11
    const int lt = blockIdx.y;         // 0..5
    const int c  = blockIdx.z;         // 0..127
    const int t  = threadIdx.x;

    #pragma unroll
    for (int u = 0; u < 8; ++u) {
        int p  = t + 256 * u;
        int li = p >> 5, mi = p & 31;
        int l = lt * 64 + li, m = mt * 32 + mi;
        float2 v = make_float2(0.f, 0.f);
        if (l < LDIM && m < MDIM)
            v = *(const float2*)(x + ((size_t)(c * LDIM + l) * MDIM + m) * 2);
        tp[0][li * 33 + mi] = v.x;
        tp[1][li * 33 + mi] = v.y;
    }
    __syncthreads();

    #pragma unroll
    for (int u = 0; u < 2; ++u) {
        int s  = t + 256 * u;          // 0..511
        int mi = s >> 4, rr = (s >> 3) & 1, lo = (s & 7) * 8;
        int m = mt * 32 + mi;
        if (m >= MDIM) continue;
        const float* pl = tp[rr];
        short8 h;
        #pragma unroll
        for (int e = 0; e < 8; ++e)
            h[e] = (short)f2bf(pl[(lo + e) * 33 + mi]);
        *(short8*)(xA + ((size_t)m * CR + 2 * c + rr) * LP + lt * 64 + lo) = h;
    }
}

// ---------------------------------------------------------------------------
// pct fp32 [m][l][k] -> pctT bf16 [m][k][LP] (l-fast, zero pad l>=361, k>=361)
// 32l x 128k tile, stride-129 pad: read & write phases <=2-way bank aliasing.
__global__ __launch_bounds__(256)
void sht_prep_pct(const float* __restrict__ pct, unsigned short* __restrict__ pctT) {
    __shared__ float tile[32][129];
    const int m  = blockIdx.y;
    const int bx = blockIdx.x;         // 0..35
    const int kt = bx % 3, lt = bx / 3;
    const int l0 = lt * 32, k0 = kt * 128;
    const int t  = threadIdx.x;

    const int kk = t & 127, lw = t >> 7;   // 2 l-rows per pass, 128 consecutive k
    #pragma unroll
    for (int u = 0; u < 16; ++u) {
        int li = lw + 2 * u;               // 0..31
        int l = l0 + li, k = k0 + kk;
        float v = 0.f;
        if (l < LDIM && k < KDIM)
            v = pct[((size_t)m * LDIM + l) * KDIM + k];
        tile[li][kk] = v;
    }
    __syncthreads();

    #pragma unroll
    for (int u = 0; u < 2; ++u) {
        int s = t + 256 * u;               // 0..511
        int ko = s >> 2, lo = (s & 3) * 8; // 128 k rows x 4 l-octets
        short8 h;
        #pragma unroll
        for (int e = 0; e < 8; ++e)
            h[e] = (short)f2bf(tile[lo + e][ko]);
        *(short8*)(pctT + ((size_t)m * KP + k0 + ko) * LP + l0 + lo) = h;
    }
}

// ---------------------------------------------------------------------------
// Stage A2: per-m GEMM D[cr][k] = sum_l xA[m][cr][l] * pctT[m][k][l]
// 512 thr, BM=128 (cr half), BN=384 (all k): xA read exactly once; the 2
// ct-blocks of one m are swizzle-adjacent so pctT panel (294 KB) L2-shares.
__global__ __launch_bounds__(512)
void sht_stageA2(const unsigned short* __restrict__ pctT, const unsigned short* __restrict__ xA,
                 unsigned short* __restrict__ xs) {
    __shared__ unsigned short As[128 * 32];   // 8 KB
    __shared__ unsigned short Bs[384 * 32];   // 24 KB

    const int p   = xcd_swz(blockIdx.x, 2 * MDIM);
    const int m   = p >> 1, ct = p & 1;
    const int c0  = ct * 128;
    const int t   = threadIdx.x;
    const int w   = t >> 6, L = t & 63;
    const int wr  = w & 1, wc = w >> 1;       // 2 M-halves x 4 N-quarters
    const int lane15 = L & 15, quad = L >> 4;
    const int arr = t >> 2, alq = t & 3;

    const unsigned short* xAm = xA + (size_t)m * CR * LP;
    const unsigned short* pTm = pctT + (size_t)m * KP * LP;

    floatx4 acc[4][6] = {};

    for (int kb = 0; kb < LP; kb += 32) {
        async_copy16(xAm + (size_t)(c0 + arr) * LP + kb + alq * 8,
                     As + (size_t)(w * 64) * 8);
        #pragma unroll
        for (int u = 0; u < 3; ++u) {
            int s = u * 512 + t;
            int rr = s >> 2, lq = s & 3;
            async_copy16(pTm + (size_t)rr * LP + kb + lq * 8,
                         Bs + (size_t)(u * 512 + w * 64) * 8);
        }
        __syncthreads();

        short8 af[4], bf[6];
        #pragma unroll
        for (int i = 0; i < 4; ++i)
            af[i] = *(const short8*)&As[((wr * 64 + i * 16 + lane15) * 4 + quad) * 8];
        #pragma unroll
        for (int j = 0; j < 6; ++j)
            bf[j] = *(const short8*)&Bs[((wc * 96 + j * 16 + lane15) * 4 + quad) * 8];
        #pragma unroll
        for (int i = 0; i < 4; ++i)
            #pragma unroll
            for (int j = 0; j < 6; ++j)
                acc[i][j] = __builtin_amdgcn_mfma_f32_16x16x32_bf16(af[i], bf[j], acc[i][j], 0, 0, 0);
        __syncthreads();
    }

    // epilogue: element (cr,k): c=cr>>1, r=cr&1 -> xs[(c*361+k)*736 + 2m+r]
    #pragma unroll
    for (int j = 0; j < 6; ++j) {
        int k = wc * 96 + j * 16 + lane15;
        if (k >= KDIM) continue;
        #pragma unroll
        for (int i = 0; i < 4; ++i) {
            #pragma unroll
            for (int eh = 0; eh < 2; ++eh) {
                int cr = c0 + wr * 64 + i * 16 + quad * 4 + eh * 2;  // even
                int c  = cr >> 1;
                unsigned pack = (unsigned)f2bf(acc[i][j][eh * 2]) |
                                ((unsigned)f2bf(acc[i][j][eh * 2 + 1]) << 16);
                *(unsigned*)(xs + (size_t)(c * KDIM + k) * MRP + 2 * m) = pack;
            }
        }
    }
}

// ---------------------------------------------------------------------------
// Stage A (fallback if workspace too small): original in-loop fp32 pct staging.
__global__ __launch_bounds__(256)
void sht_stageA(const float* __restrict__ pct, const unsigned short* __restrict__ xA,
                unsigned short* __restrict__ xs) {
    __shared__ unsigned short As[128 * 32];
    __shared__ unsigned short Bs[32 * 130];

    const int m   = blockIdx.y;
    const int ct  = blockIdx.x & 1;
    const int kt  = blockIdx.x >> 1;
    const int c0  = ct * 128;
    const int n0  = kt * 128;
    const int t   = threadIdx.x;
    const int w   = t >> 6, L = t & 63;
    const int wr  = w & 1, wc = w >> 1;
    const int lane15 = L & 15, quad = L >> 4;
    const int bl = t >> 3, bkq = t & 7;

    const unsigned short* xAm = xA + (size_t)m * CR * LP;
    const float* pctm = pct + (size_t)m * LDIM * KDIM;

    floatx4 acc[4][4] = {};

    for (int kb = 0; kb < LP; kb += 32) {
        #pragma unroll
        for (int i = 0; i < 2; ++i) {
            int s = w * 128 + i * 64 + L;
            int cr = s >> 2, lq = s & 3;
            async_copy16(xAm + (size_t)(c0 + cr) * LP + kb + lq * 8,
                         As + (size_t)(w * 128 + i * 64) * 8);
        }
        {
            int l = kb + bl;
            bool lok = (l < LDIM);
            const float* prow = pctm + (size_t)l * KDIM;
            #pragma unroll
            for (int u = 0; u < 4; ++u) {
                int kc = n0 + u * 32 + bkq * 4;
                float f0 = (lok && kc + 0 < KDIM) ? prow[kc + 0] : 0.f;
                float f1 = (lok && kc + 1 < KDIM) ? prow[kc + 1] : 0.f;
                float f2 = (lok && kc + 2 < KDIM) ? prow[kc + 2] : 0.f;
                float f3 = (lok && kc + 3 < KDIM) ? prow[kc + 3] : 0.f;
                unsigned* bp = (unsigned*)&Bs[bl * 130 + u * 32 + bkq * 4];
                bp[0] = (unsigned)f2bf(f0) | ((unsigned)f2bf(f1) << 16);
                bp[1] = (unsigned)f2bf(f2) | ((unsigned)f2bf(f3) << 16);
            }
        }
        __syncthreads();

        short8 af[4];
        #pragma unroll
        for (int i = 0; i < 4; ++i) {
            int row = wr * 64 + i * 16 + lane15;
            af[i] = *(const short8*)&As[(row * 4 + quad) * 8];
        }
        #pragma unroll
        for (int jf = 0; jf < 4; ++jf) {
            int col = wc * 64 + jf * 16 + lane15;
            short8 bf;
            #pragma unroll
            for (int j = 0; j < 8; ++j)
                bf[j] = (short)Bs[(quad * 8 + j) * 130 + col];
            #pragma unroll
            for (int i = 0; i < 4; ++i)
                acc[i][jf] = __builtin_amdgcn_mfma_f32_16x16x32_bf16(af[i], bf, acc[i][jf], 0, 0, 0);
        }
        __syncthreads();
    }

    #pragma unroll
    for (int i = 0; i < 4; ++i) {
        #pragma unroll
        for (int jf = 0; jf < 4; ++jf) {
            int k = n0 + wc * 64 + jf * 16 + lane15;
            if (k >= KDIM) continue;
            #pragma unroll
            for (int eh = 0; eh < 2; ++eh) {
                int cr = c0 + wr * 64 + i * 16 + quad * 4 + eh * 2;
                int c  = cr >> 1;
                unsigned pack = (unsigned)f2bf(acc[i][jf][eh * 2]) |
                                ((unsigned)f2bf(acc[i][jf][eh * 2 + 1]) << 16);
                *(unsigned*)(xs + (size_t)(c * KDIM + k) * MRP + 2 * m) = pack;
            }
        }
    }
}

// ---------------------------------------------------------------------------
// Stage B2: out[ck][j] = sum_mr xs[ck][mr] * Tp[j][mr]
// 512 thr, BM=128 (ck), BN=384 (n half): xs read exactly 2x (was 6x).
__global__ __launch_bounds__(512)
void sht_stageB2(const unsigned short* __restrict__ xs, const unsigned short* __restrict__ Tp,
                 float* __restrict__ out) {
    __shared__ unsigned short As[128 * 32];   // 8 KB
    __shared__ unsigned short Bs[384 * 32];   // 24 KB

    const int p   = xcd_swz(blockIdx.x, 2 * MDIM);
    const int ckt = p >> 1, nt = p & 1;
    const int ck0 = ckt * 128, n0 = nt * 384;
    const int t   = threadIdx.x;
    const int w   = t >> 6, L = t & 63;
    const int wr  = w & 1, wc = w >> 1;
    const int lane15 = L & 15, quad = L >> 4;
    const int arr = t >> 2, alq = t & 3;

    floatx4 acc[4][6] = {};

    for (int kb = 0; kb < MRP; kb += 32) {
        async_copy16(xs + (size_t)(ck0 + arr) * MRP + kb + alq * 8,
                     As + (size_t)(w * 64) * 8);
        #pragma unroll
        for (int u = 0; u < 3; ++u) {
            int s = u * 512 + t;
            int rr = s >> 2, lq = s & 3;
            async_copy16(Tp + (size_t)(n0 + rr) * MRP + kb + lq * 8,
                         Bs + (size_t)(u * 512 + w * 64) * 8);
        }
        __syncthreads();

        short8 af[4], bf[6];
        #pragma unroll
        for (int i = 0; i < 4; ++i)
            af[i] = *(const short8*)&As[((wr * 64 + i * 16 + lane15) * 4 + quad) * 8];
        #pragma unroll
        for (int j = 0; j < 6; ++j)
            bf[j] = *(const short8*)&Bs[((wc * 96 + j * 16 + lane15) * 4 + quad) * 8];
        #pragma unroll
        for (int i = 0; i < 4; ++i)
            #pragma unroll
            for (int j = 0; j < 6; ++j)
                acc[i][j] = __builtin_amdgcn_mfma_f32_16x16x32_bf16(af[i], bf[j], acc[i][j], 0, 0, 0);
        __syncthreads();
    }

    #pragma unroll
    for (int i = 0; i < 4; ++i) {
        int ckr = ck0 + wr * 64 + i * 16 + quad * 4;
        #pragma unroll
        for (int j = 0; j < 6; ++j) {
            int jj = n0 + wc * 96 + j * 16 + lane15;
            if (jj >= NLON) continue;
            #pragma unroll
            for (int e = 0; e < 4; ++e)
                out[(size_t)(ckr + e) * NLON + jj] = acc[i][j][e];
        }
    }
}

// ---------------------------------------------------------------------------
extern "C" void kernel_launch(void* const* d_in, const int* in_sizes, int n_in,
                              void* d_out, int out_size, void* d_ws, size_t ws_size,
                              hipStream_t stream) {
    const float* x   = (const float*)d_in[0];   // [1,128,361,361,2] fp32
    const float* pct = (const float*)d_in[1];   // [361,361,361] fp32
    float* out = (float*)d_out;                 // [1,128,361,720] fp32

    unsigned short* xs = (unsigned short*)d_ws;              // CK*MRP bf16 (68.0 MB)
    unsigned short* Tp = xs + (size_t)CK * MRP;              // NP*MRP bf16 (1.13 MB)
    unsigned short* xA = (unsigned short*)d_out;             // 361*256*384 bf16 (71 MB, dead before stage B)

    const size_t base_shorts = (size_t)CK * MRP + (size_t)NP * MRP;
    const size_t pctT_shorts = (size_t)MDIM * KP * LP;       // 106.5 MB
    const bool fast = ws_size >= (base_shorts + pctT_shorts) * sizeof(unsigned short);

    sht_gen_T<<<(NP * MRP + 255) / 256, 256, 0, stream>>>(Tp);
    sht_prep_x<<<dim3(12, 6, 128), 256, 0, stream>>>(x, xA);
    if (fast) {
        unsigned short* pctT = Tp + (size_t)NP * MRP;
        sht_prep_pct<<<dim3(36, MDIM), 256, 0, stream>>>(pct, pctT);
        sht_stageA2<<<dim3(2 * MDIM), 512, 0, stream>>>(pctT, xA, xs);
    } else {
        sht_stageA<<<dim3(6, MDIM), 256, 0, stream>>>(pct, xA, xs);
    }
    sht_stageB2<<<dim3(2 * MDIM), 512, 0, stream>>>(xs, Tp, out);
}

// Round 4
// 646.570 us; speedup vs baseline: 1.1237x; 1.0455x over previous
//
#include <hip/hip_runtime.h>
#include <cstddef>

#define CC   128
#define LDIM 361
#define MDIM 361
#define KDIM 361
#define NLON 720
#define LP   384          // padded l (stage A K-dim)
#define KP   384          // padded k rows for pctT
#define KTP  384          // xsT row stride (k-contiguous)
#define MRP  736          // padded mr (stage B K-dim)
#define NP   768          // padded n (stage B N-dim)
#define CK   (CC*KDIM)    // 46208
#define CR   (2*CC)       // 256

typedef __attribute__((ext_vector_type(8))) short short8;
typedef __attribute__((ext_vector_type(4))) float floatx4;

__device__ __forceinline__ unsigned short f2bf(float f) {
    union { float f; unsigned u; } v; v.f = f;
    unsigned u = v.u;
    u += 0x7fffu + ((u >> 16) & 1u);   // RNE
    return (unsigned short)(u >> 16);
}

__device__ __forceinline__ void async_copy16(const void* g, void* l) {
    __builtin_amdgcn_global_load_lds(
        (const __attribute__((address_space(1))) void*)g,
        (__attribute__((address_space(3))) void*)l, 16, 0, 0);
}

// Bijective XCD-chunk swizzle (m204).
__device__ __forceinline__ int xcd_swz(int id, int P) {
    int x = id & 7, g = id >> 3;
    int q = P >> 3, r = P & 7;
    int start = (x < r) ? x * (q + 1) : r * (q + 1) + (x - r) * q;
    return start + g;
}

// ---------------------------------------------------------------------------
// Tp[n][mr] bf16, n<720 & mr<722 real weights, else 0 (pad kills xs poison).
__global__ void sht_gen_T(unsigned short* __restrict__ Tp) {
    int idx = blockIdx.x * 256 + threadIdx.x;
    if (idx >= NP * MRP) return;
    int n = idx / MRP, mr = idx - n * MRP;
    float v = 0.f;
    if (n < NLON && mr < 2 * MDIM) {
        int m = mr >> 1, im = mr & 1;
        if (m == 0)            v = im ? 0.f : 1.f;
        else if (m == MDIM-1)  v = im ? 0.f : ((n & 1) ? -1.f : 1.f);
        else {
            int ph = (m * n) % NLON;
            float ang = (float)ph * (float)(3.14159265358979323846 / 360.0);
            v = im ? (-2.f * sinf(ang)) : (2.f * cosf(ang));
        }
    }
    Tp[idx] = f2bf(v);
}

// ---------------------------------------------------------------------------
// x fp32 [c][l][m][r] -> xA bf16 [m][cr=2c+r][LP]  (round-1 measured version)
__global__ __launch_bounds__(256)
void sht_prep_x(const float* __restrict__ x, unsigned short* __restrict__ xA) {
    __shared__ float2 tile[64][33];    // [l][m]
    const int mt = blockIdx.x;         // 0..11
    const int lt = blockIdx.y;         // 0..5
    const int c  = blockIdx.z;         // 0..127
    const int t  = threadIdx.x;

    #pragma unroll
    for (int u = 0; u < 8; ++u) {
        int p  = t + 256 * u;
        int li = p >> 5, mi = p & 31;
        int l = lt * 64 + li, m = mt * 32 + mi;
        float2 v = make_float2(0.f, 0.f);
        if (l < LDIM && m < MDIM)
            v = *(const float2*)(x + ((size_t)(c * LDIM + l) * MDIM + m) * 2);
        tile[li][mi] = v;
    }
    __syncthreads();

    #pragma unroll
    for (int u = 0; u < 2; ++u) {
        int s  = t + 256 * u;          // 0..511
        int mi = s >> 4, rr = (s >> 3) & 1, lo = (s & 7) * 8;
        int m = mt * 32 + mi;
        if (m >= MDIM) continue;
        short8 h;
        #pragma unroll
        for (int e = 0; e < 8; ++e) {
            float2 p = tile[lo + e][mi];
            h[e] = (short)f2bf(rr ? p.y : p.x);
        }
        *(short8*)(xA + ((size_t)m * CR + 2 * c + rr) * LP + lt * 64 + lo) = h;
    }
}

// ---------------------------------------------------------------------------
// pct fp32 [m][l][k] -> pctT bf16 [m][k][LP]  (round-1 measured version)
__global__ __launch_bounds__(256)
void sht_prep_pct(const float* __restrict__ pct, unsigned short* __restrict__ pctT) {
    __shared__ float tile[32][33];
    const int m  = blockIdx.y;
    const int kt = blockIdx.x % 12;
    const int lt = blockIdx.x / 12;
    const int l0 = lt * 32, k0 = kt * 32;
    const int t  = threadIdx.x;

    const int ki = t & 31, lbase = t >> 5;
    #pragma unroll
    for (int u = 0; u < 4; ++u) {
        int li = lbase + 8 * u;
        int l = l0 + li, k = k0 + ki;
        float v = 0.f;
        if (l < LDIM && k < KDIM)
            v = pct[((size_t)m * LDIM + l) * KDIM + k];
        tile[li][ki] = v;
    }
    __syncthreads();

    const int ko = t >> 3, lo = (t & 7) * 4;
    unsigned pk0 = (unsigned)f2bf(tile[lo + 0][ko]) | ((unsigned)f2bf(tile[lo + 1][ko]) << 16);
    unsigned pk1 = (unsigned)f2bf(tile[lo + 2][ko]) | ((unsigned)f2bf(tile[lo + 3][ko]) << 16);
    unsigned* dst = (unsigned*)(pctT + ((size_t)m * KP + k0 + ko) * LP + l0 + lo);
    dst[0] = pk0; dst[1] = pk1;
}

// ---------------------------------------------------------------------------
// Stage A3: per-m GEMM D[cr][k] = sum_l xA[m][cr][l] * pctT[m][k][l]
// COALESCED epilogue: writes xsT bf16 [m][cr][KTP] (k-contiguous), no scatter.
__global__ __launch_bounds__(512)
void sht_stageA3(const unsigned short* __restrict__ pctT, const unsigned short* __restrict__ xA,
                 unsigned short* __restrict__ xsT) {
    __shared__ unsigned short As[128 * 32];   // 8 KB
    __shared__ unsigned short Bs[384 * 32];   // 24 KB

    const int p   = xcd_swz(blockIdx.x, 2 * MDIM);
    const int m   = p >> 1, ct = p & 1;
    const int c0  = ct * 128;
    const int t   = threadIdx.x;
    const int w   = t >> 6, L = t & 63;
    const int wr  = w & 1, wc = w >> 1;
    const int lane15 = L & 15, quad = L >> 4;
    const int arr = t >> 2, alq = t & 3;

    const unsigned short* xAm = xA + (size_t)m * CR * LP;
    const unsigned short* pTm = pctT + (size_t)m * KP * LP;

    floatx4 acc[4][6] = {};

    for (int kb = 0; kb < LP; kb += 32) {
        async_copy16(xAm + (size_t)(c0 + arr) * LP + kb + alq * 8,
                     As + (size_t)(w * 64) * 8);
        #pragma unroll
        for (int u = 0; u < 3; ++u) {
            int s = u * 512 + t;
            int rr = s >> 2, lq = s & 3;
            async_copy16(pTm + (size_t)rr * LP + kb + lq * 8,
                         Bs + (size_t)(u * 512 + w * 64) * 8);
        }
        __syncthreads();

        short8 af[4], bf[6];
        #pragma unroll
        for (int i = 0; i < 4; ++i)
            af[i] = *(const short8*)&As[((wr * 64 + i * 16 + lane15) * 4 + quad) * 8];
        #pragma unroll
        for (int j = 0; j < 6; ++j)
            bf[j] = *(const short8*)&Bs[((wc * 96 + j * 16 + lane15) * 4 + quad) * 8];
        #pragma unroll
        for (int i = 0; i < 4; ++i)
            #pragma unroll
            for (int j = 0; j < 6; ++j)
                acc[i][j] = __builtin_amdgcn_mfma_f32_16x16x32_bf16(af[i], bf[j], acc[i][j], 0, 0, 0);
        __syncthreads();
    }

    // coalesced: lane15 -> consecutive k; 16-lane group = 32B contiguous
    #pragma unroll
    for (int i = 0; i < 4; ++i) {
        #pragma unroll
        for (int j = 0; j < 6; ++j) {
            int k = wc * 96 + j * 16 + lane15;
            #pragma unroll
            for (int e = 0; e < 4; ++e) {
                int cr = c0 + wr * 64 + i * 16 + quad * 4 + e;
                xsT[((size_t)m * CR + cr) * KTP + k] = f2bf(acc[i][j][e]);
            }
        }
    }
}

// ---------------------------------------------------------------------------
// xsT bf16 [m][cr][KTP] -> xs bf16 [ck][MRP]; both sides coalesced via LDS.
__global__ __launch_bounds__(256)
void sht_xs_tr(const unsigned short* __restrict__ xsT, unsigned short* __restrict__ xs) {
    __shared__ unsigned short tile[128 * 65];
    const int c  = blockIdx.y;          // 0..127
    const int bx = blockIdx.x;          // 0..35
    const int mt = bx / 6, kt = bx % 6;
    const int m0 = mt * 64, k0 = kt * 64;
    const int t  = threadIdx.x;

    // read: 1024 16B chunks; chunk q: rho=q>>3 (mi=rho>>1, r=rho&1), ko8=q&7
    #pragma unroll
    for (int u = 0; u < 4; ++u) {
        int q = t + 256 * u;
        int rho = q >> 3, ko8 = q & 7;
        int mi = rho >> 1, r = rho & 1;
        int m = m0 + mi;
        short8 v = {};
        if (m < MDIM)
            v = *(const short8*)(xsT + ((size_t)m * CR + 2 * c + r) * KTP + k0 + ko8 * 8);
        *(short8*)&tile[rho * 65 + ko8 * 8] = v;
    }
    __syncthreads();

    // write: 1024 16B chunks; q: kk=q>>4, mc=q&15
    #pragma unroll
    for (int u = 0; u < 4; ++u) {
        int q = t + 256 * u;
        int kk = q >> 4, mc = q & 15;
        int k = k0 + kk;
        int mr0 = 2 * m0 + mc * 8;
        if (k >= KDIM || mr0 >= MRP) continue;
        short8 h;
        #pragma unroll
        for (int e = 0; e < 8; ++e)
            h[e] = (short)tile[(mc * 8 + e) * 65 + kk];
        *(short8*)(xs + (size_t)(c * KDIM + k) * MRP + mr0) = h;
    }
}

// ---------------------------------------------------------------------------
// Stage A2 (fast1): scatter epilogue direct to xs (round-3 measured, 148us).
__global__ __launch_bounds__(512)
void sht_stageA2(const unsigned short* __restrict__ pctT, const unsigned short* __restrict__ xA,
                 unsigned short* __restrict__ xs) {
    __shared__ unsigned short As[128 * 32];
    __shared__ unsigned short Bs[384 * 32];

    const int p   = xcd_swz(blockIdx.x, 2 * MDIM);
    const int m   = p >> 1, ct = p & 1;
    const int c0  = ct * 128;
    const int t   = threadIdx.x;
    const int w   = t >> 6, L = t & 63;
    const int wr  = w & 1, wc = w >> 1;
    const int lane15 = L & 15, quad = L >> 4;
    const int arr = t >> 2, alq = t & 3;

    const unsigned short* xAm = xA + (size_t)m * CR * LP;
    const unsigned short* pTm = pctT + (size_t)m * KP * LP;

    floatx4 acc[4][6] = {};

    for (int kb = 0; kb < LP; kb += 32) {
        async_copy16(xAm + (size_t)(c0 + arr) * LP + kb + alq * 8,
                     As + (size_t)(w * 64) * 8);
        #pragma unroll
        for (int u = 0; u < 3; ++u) {
            int s = u * 512 + t;
            int rr = s >> 2, lq = s & 3;
            async_copy16(pTm + (size_t)rr * LP + kb + lq * 8,
                         Bs + (size_t)(u * 512 + w * 64) * 8);
        }
        __syncthreads();

        short8 af[4], bf[6];
        #pragma unroll
        for (int i = 0; i < 4; ++i)
            af[i] = *(const short8*)&As[((wr * 64 + i * 16 + lane15) * 4 + quad) * 8];
        #pragma unroll
        for (int j = 0; j < 6; ++j)
            bf[j] = *(const short8*)&Bs[((wc * 96 + j * 16 + lane15) * 4 + quad) * 8];
        #pragma unroll
        for (int i = 0; i < 4; ++i)
            #pragma unroll
            for (int j = 0; j < 6; ++j)
                acc[i][j] = __builtin_amdgcn_mfma_f32_16x16x32_bf16(af[i], bf[j], acc[i][j], 0, 0, 0);
        __syncthreads();
    }

    #pragma unroll
    for (int j = 0; j < 6; ++j) {
        int k = wc * 96 + j * 16 + lane15;
        if (k >= KDIM) continue;
        #pragma unroll
        for (int i = 0; i < 4; ++i) {
            #pragma unroll
            for (int eh = 0; eh < 2; ++eh) {
                int cr = c0 + wr * 64 + i * 16 + quad * 4 + eh * 2;
                int c  = cr >> 1;
                unsigned pack = (unsigned)f2bf(acc[i][j][eh * 2]) |
                                ((unsigned)f2bf(acc[i][j][eh * 2 + 1]) << 16);
                *(unsigned*)(xs + (size_t)(c * KDIM + k) * MRP + 2 * m) = pack;
            }
        }
    }
}

// ---------------------------------------------------------------------------
// Stage A (tier0 fallback): original in-loop fp32 pct staging.
__global__ __launch_bounds__(256)
void sht_stageA(const float* __restrict__ pct, const unsigned short* __restrict__ xA,
                unsigned short* __restrict__ xs) {
    __shared__ unsigned short As[128 * 32];
    __shared__ unsigned short Bs[32 * 130];

    const int m   = blockIdx.y;
    const int ct  = blockIdx.x & 1;
    const int kt  = blockIdx.x >> 1;
    const int c0  = ct * 128;
    const int n0  = kt * 128;
    const int t   = threadIdx.x;
    const int w   = t >> 6, L = t & 63;
    const int wr  = w & 1, wc = w >> 1;
    const int lane15 = L & 15, quad = L >> 4;
    const int bl = t >> 3, bkq = t & 7;

    const unsigned short* xAm = xA + (size_t)m * CR * LP;
    const float* pctm = pct + (size_t)m * LDIM * KDIM;

    floatx4 acc[4][4] = {};

    for (int kb = 0; kb < LP; kb += 32) {
        #pragma unroll
        for (int i = 0; i < 2; ++i) {
            int s = w * 128 + i * 64 + L;
            int cr = s >> 2, lq = s & 3;
            async_copy16(xAm + (size_t)(c0 + cr) * LP + kb + lq * 8,
                         As + (size_t)(w * 128 + i * 64) * 8);
        }
        {
            int l = kb + bl;
            bool lok = (l < LDIM);
            const float* prow = pctm + (size_t)l * KDIM;
            #pragma unroll
            for (int u = 0; u < 4; ++u) {
                int kc = n0 + u * 32 + bkq * 4;
                float f0 = (lok && kc + 0 < KDIM) ? prow[kc + 0] : 0.f;
                float f1 = (lok && kc + 1 < KDIM) ? prow[kc + 1] : 0.f;
                float f2 = (lok && kc + 2 < KDIM) ? prow[kc + 2] : 0.f;
                float f3 = (lok && kc + 3 < KDIM) ? prow[kc + 3] : 0.f;
                unsigned* bp = (unsigned*)&Bs[bl * 130 + u * 32 + bkq * 4];
                bp[0] = (unsigned)f2bf(f0) | ((unsigned)f2bf(f1) << 16);
                bp[1] = (unsigned)f2bf(f2) | ((unsigned)f2bf(f3) << 16);
            }
        }
        __syncthreads();

        short8 af[4];
        #pragma unroll
        for (int i = 0; i < 4; ++i) {
            int row = wr * 64 + i * 16 + lane15;
            af[i] = *(const short8*)&As[(row * 4 + quad) * 8];
        }
        #pragma unroll
        for (int jf = 0; jf < 4; ++jf) {
            int col = wc * 64 + jf * 16 + lane15;
            short8 bf;
            #pragma unroll
            for (int j = 0; j < 8; ++j)
                bf[j] = (short)Bs[(quad * 8 + j) * 130 + col];
            #pragma unroll
            for (int i = 0; i < 4; ++i)
                acc[i][jf] = __builtin_amdgcn_mfma_f32_16x16x32_bf16(af[i], bf, acc[i][jf], 0, 0, 0);
        }
        __syncthreads();
    }

    #pragma unroll
    for (int i = 0; i < 4; ++i) {
        #pragma unroll
        for (int jf = 0; jf < 4; ++jf) {
            int k = n0 + wc * 64 + jf * 16 + lane15;
            if (k >= KDIM) continue;
            #pragma unroll
            for (int eh = 0; eh < 2; ++eh) {
                int cr = c0 + wr * 64 + i * 16 + quad * 4 + eh * 2;
                int c  = cr >> 1;
                unsigned pack = (unsigned)f2bf(acc[i][jf][eh * 2]) |
                                ((unsigned)f2bf(acc[i][jf][eh * 2 + 1]) << 16);
                *(unsigned*)(xs + (size_t)(c * KDIM + k) * MRP + 2 * m) = pack;
            }
        }
    }
}

// ---------------------------------------------------------------------------
// Stage B2: out[ck][j] = sum_mr xs[ck][mr] * Tp[j][mr]  (round-3, kept)
__global__ __launch_bounds__(512)
void sht_stageB2(const unsigned short* __restrict__ xs, const unsigned short* __restrict__ Tp,
                 float* __restrict__ out) {
    __shared__ unsigned short As[128 * 32];
    __shared__ unsigned short Bs[384 * 32];

    const int p   = xcd_swz(blockIdx.x, 2 * MDIM);
    const int ckt = p >> 1, nt = p & 1;
    const int ck0 = ckt * 128, n0 = nt * 384;
    const int t   = threadIdx.x;
    const int w   = t >> 6, L = t & 63;
    const int wr  = w & 1, wc = w >> 1;
    const int lane15 = L & 15, quad = L >> 4;
    const int arr = t >> 2, alq = t & 3;

    floatx4 acc[4][6] = {};

    for (int kb = 0; kb < MRP; kb += 32) {
        async_copy16(xs + (size_t)(ck0 + arr) * MRP + kb + alq * 8,
                     As + (size_t)(w * 64) * 8);
        #pragma unroll
        for (int u = 0; u < 3; ++u) {
            int s = u * 512 + t;
            int rr = s >> 2, lq = s & 3;
            async_copy16(Tp + (size_t)(n0 + rr) * MRP + kb + lq * 8,
                         Bs + (size_t)(u * 512 + w * 64) * 8);
        }
        __syncthreads();

        short8 af[4], bf[6];
        #pragma unroll
        for (int i = 0; i < 4; ++i)
            af[i] = *(const short8*)&As[((wr * 64 + i * 16 + lane15) * 4 + quad) * 8];
        #pragma unroll
        for (int j = 0; j < 6; ++j)
            bf[j] = *(const short8*)&Bs[((wc * 96 + j * 16 + lane15) * 4 + quad) * 8];
        #pragma unroll
        for (int i = 0; i < 4; ++i)
            #pragma unroll
            for (int j = 0; j < 6; ++j)
                acc[i][j] = __builtin_amdgcn_mfma_f32_16x16x32_bf16(af[i], bf[j], acc[i][j], 0, 0, 0);
        __syncthreads();
    }

    #pragma unroll
    for (int i = 0; i < 4; ++i) {
        int ckr = ck0 + wr * 64 + i * 16 + quad * 4;
        #pragma unroll
        for (int j = 0; j < 6; ++j) {
            int jj = n0 + wc * 96 + j * 16 + lane15;
            if (jj >= NLON) continue;
            #pragma unroll
            for (int e = 0; e < 4; ++e)
                out[(size_t)(ckr + e) * NLON + jj] = acc[i][j][e];
        }
    }
}

// ---------------------------------------------------------------------------
extern "C" void kernel_launch(void* const* d_in, const int* in_sizes, int n_in,
                              void* d_out, int out_size, void* d_ws, size_t ws_size,
                              hipStream_t stream) {
    const float* x   = (const float*)d_in[0];   // [1,128,361,361,2] fp32
    const float* pct = (const float*)d_in[1];   // [361,361,361] fp32
    float* out = (float*)d_out;                 // [1,128,361,720] fp32

    unsigned short* xs = (unsigned short*)d_ws;              // CK*MRP (68.0 MB)
    unsigned short* Tp = xs + (size_t)CK * MRP;              // NP*MRP (1.13 MB)
    unsigned short* xA = (unsigned short*)d_out;             // dead before stage B

    const size_t base_shorts = (size_t)CK * MRP + (size_t)NP * MRP;
    const size_t pctT_shorts = (size_t)MDIM * KP * LP;       // 106.5 MB
    const size_t xsT_shorts  = (size_t)MDIM * CR * KTP;      // 71.0 MB
    const bool fast1 = ws_size >= (base_shorts + pctT_shorts) * sizeof(unsigned short);
    const bool fast2 = ws_size >= (base_shorts + pctT_shorts + xsT_shorts) * sizeof(unsigned short);

    sht_gen_T<<<(NP * MRP + 255) / 256, 256, 0, stream>>>(Tp);
    sht_prep_x<<<dim3(12, 6, 128), 256, 0, stream>>>(x, xA);
    if (fast2) {
        unsigned short* pctT = Tp + (size_t)NP * MRP;
        unsigned short* xsT  = pctT + pctT_shorts;
        sht_prep_pct<<<dim3(144, MDIM), 256, 0, stream>>>(pct, pctT);
        sht_stageA3<<<dim3(2 * MDIM), 512, 0, stream>>>(pctT, xA, xsT);
        sht_xs_tr<<<dim3(36, 128), 256, 0, stream>>>(xsT, xs);
    } else if (fast1) {
        unsigned short* pctT = Tp + (size_t)NP * MRP;
        sht_prep_pct<<<dim3(144, MDIM), 256, 0, stream>>>(pct, pctT);
        sht_stageA2<<<dim3(2 * MDIM), 512, 0, stream>>>(pctT, xA, xs);
    } else {
        sht_stageA<<<dim3(6, MDIM), 256, 0, stream>>>(pct, xA, xs);
    }
    sht_stageB2<<<dim3(2 * MDIM), 512, 0, stream>>>(xs, Tp, out);
}

// Round 5
// 626.724 us; speedup vs baseline: 1.1593x; 1.0317x over previous
//
#include <hip/hip_runtime.h>
#include <cstddef>

#define CC   128
#define LDIM 361
#define MDIM 361
#define KDIM 361
#define NLON 720
#define LP   384          // padded l (stage A K-dim)
#define KP   384          // padded k rows for pctT
#define KTP  384          // xsT row stride (k-contiguous)
#define MRP  736          // padded mr (stage B K-dim)
#define NP   768          // padded n (stage B N-dim)
#define CK   (CC*KDIM)    // 46208
#define CR   (2*CC)       // 256

typedef __attribute__((ext_vector_type(8))) short short8;
typedef __attribute__((ext_vector_type(4))) float floatx4;

__device__ __forceinline__ unsigned short f2bf(float f) {
    union { float f; unsigned u; } v; v.f = f;
    unsigned u = v.u;
    u += 0x7fffu + ((u >> 16) & 1u);   // RNE
    return (unsigned short)(u >> 16);
}

__device__ __forceinline__ void async_copy16(const void* g, void* l) {
    __builtin_amdgcn_global_load_lds(
        (const __attribute__((address_space(1))) void*)g,
        (__attribute__((address_space(3))) void*)l, 16, 0, 0);
}

// Bijective XCD-chunk swizzle (m204).
__device__ __forceinline__ int xcd_swz(int id, int P) {
    int x = id & 7, g = id >> 3;
    int q = P >> 3, r = P & 7;
    int start = (x < r) ? x * (q + 1) : r * (q + 1) + (x - r) * q;
    return start + g;
}

// ---------------------------------------------------------------------------
// Tp[n][mr] bf16, n<720 & mr<722 real weights, else 0 (pad kills xs poison).
__global__ void sht_gen_T(unsigned short* __restrict__ Tp) {
    int idx = blockIdx.x * 256 + threadIdx.x;
    if (idx >= NP * MRP) return;
    int n = idx / MRP, mr = idx - n * MRP;
    float v = 0.f;
    if (n < NLON && mr < 2 * MDIM) {
        int m = mr >> 1, im = mr & 1;
        if (m == 0)            v = im ? 0.f : 1.f;
        else if (m == MDIM-1)  v = im ? 0.f : ((n & 1) ? -1.f : 1.f);
        else {
            int ph = (m * n) % NLON;
            float ang = (float)ph * (float)(3.14159265358979323846 / 360.0);
            v = im ? (-2.f * sinf(ang)) : (2.f * cosf(ang));
        }
    }
    Tp[idx] = f2bf(v);
}

// ---------------------------------------------------------------------------
// x fp32 [c][l][m][r] -> xA bf16 [m][cr=2c+r][LP]  (round-1 measured version)
__global__ __launch_bounds__(256)
void sht_prep_x(const float* __restrict__ x, unsigned short* __restrict__ xA) {
    __shared__ float2 tile[64][33];    // [l][m]
    const int mt = blockIdx.x;         // 0..11
    const int lt = blockIdx.y;         // 0..5
    const int c  = blockIdx.z;         // 0..127
    const int t  = threadIdx.x;

    #pragma unroll
    for (int u = 0; u < 8; ++u) {
        int p  = t + 256 * u;
        int li = p >> 5, mi = p & 31;
        int l = lt * 64 + li, m = mt * 32 + mi;
        float2 v = make_float2(0.f, 0.f);
        if (l < LDIM && m < MDIM)
            v = *(const float2*)(x + ((size_t)(c * LDIM + l) * MDIM + m) * 2);
        tile[li][mi] = v;
    }
    __syncthreads();

    #pragma unroll
    for (int u = 0; u < 2; ++u) {
        int s  = t + 256 * u;          // 0..511
        int mi = s >> 4, rr = (s >> 3) & 1, lo = (s & 7) * 8;
        int m = mt * 32 + mi;
        if (m >= MDIM) continue;
        short8 h;
        #pragma unroll
        for (int e = 0; e < 8; ++e) {
            float2 p = tile[lo + e][mi];
            h[e] = (short)f2bf(rr ? p.y : p.x);
        }
        *(short8*)(xA + ((size_t)m * CR + 2 * c + rr) * LP + lt * 64 + lo) = h;
    }
}

// ---------------------------------------------------------------------------
// pct fp32 [m][l][k] -> pctT bf16 [m][k][LP]  (round-1 measured version)
__global__ __launch_bounds__(256)
void sht_prep_pct(const float* __restrict__ pct, unsigned short* __restrict__ pctT) {
    __shared__ float tile[32][33];
    const int m  = blockIdx.y;
    const int kt = blockIdx.x % 12;
    const int lt = blockIdx.x / 12;
    const int l0 = lt * 32, k0 = kt * 32;
    const int t  = threadIdx.x;

    const int ki = t & 31, lbase = t >> 5;
    #pragma unroll
    for (int u = 0; u < 4; ++u) {
        int li = lbase + 8 * u;
        int l = l0 + li, k = k0 + ki;
        float v = 0.f;
        if (l < LDIM && k < KDIM)
            v = pct[((size_t)m * LDIM + l) * KDIM + k];
        tile[li][ki] = v;
    }
    __syncthreads();

    const int ko = t >> 3, lo = (t & 7) * 4;
    unsigned pk0 = (unsigned)f2bf(tile[lo + 0][ko]) | ((unsigned)f2bf(tile[lo + 1][ko]) << 16);
    unsigned pk1 = (unsigned)f2bf(tile[lo + 2][ko]) | ((unsigned)f2bf(tile[lo + 3][ko]) << 16);
    unsigned* dst = (unsigned*)(pctT + ((size_t)m * KP + k0 + ko) * LP + l0 + lo);
    dst[0] = pk0; dst[1] = pk1;
}

// ---------------------------------------------------------------------------
// Stage A4: per-m GEMM D[cr][k] = sum_l xA[m][cr][l] * pctT[m][k][l]
// Double-buffered 2-phase: STAGE(next) issued before compute(cur); the single
// end-of-iter __syncthreads (vmcnt0+lgkmcnt0) drains loads that had the whole
// compute phase to land. Coalesced xsT epilogue.
__global__ __launch_bounds__(512)
void sht_stageA4(const unsigned short* __restrict__ pctT, const unsigned short* __restrict__ xA,
                 unsigned short* __restrict__ xsT) {
    __shared__ unsigned short As[2][128 * 32];   // 16 KB
    __shared__ unsigned short Bs[2][384 * 32];   // 48 KB

    const int p   = xcd_swz(blockIdx.x, 2 * MDIM);
    const int m   = p >> 1, ct = p & 1;
    const int c0  = ct * 128;
    const int t   = threadIdx.x;
    const int w   = t >> 6, L = t & 63;
    const int wr  = w & 1, wc = w >> 1;
    const int lane15 = L & 15, quad = L >> 4;
    const int arr = t >> 2, alq = t & 3;

    const unsigned short* xAm = xA + (size_t)m * CR * LP;
    const unsigned short* pTm = pctT + (size_t)m * KP * LP;

    floatx4 acc[4][6] = {};

    auto stage = [&](int buf, int kb) {
        async_copy16(xAm + (size_t)(c0 + arr) * LP + kb + alq * 8,
                     &As[buf][(w * 64) * 8]);
        #pragma unroll
        for (int u = 0; u < 3; ++u) {
            int s = u * 512 + t;
            int rr = s >> 2, lq = s & 3;
            async_copy16(pTm + (size_t)rr * LP + kb + lq * 8,
                         &Bs[buf][(u * 512 + w * 64) * 8]);
        }
    };

    const int NT = LP / 32;    // 12
    stage(0, 0);
    __syncthreads();

    int cur = 0;
    for (int it = 0; it < NT; ++it) {
        if (it + 1 < NT) stage(cur ^ 1, (it + 1) * 32);

        short8 af[4], bf[6];
        #pragma unroll
        for (int i = 0; i < 4; ++i)
            af[i] = *(const short8*)&As[cur][((wr * 64 + i * 16 + lane15) * 4 + quad) * 8];
        #pragma unroll
        for (int j = 0; j < 6; ++j)
            bf[j] = *(const short8*)&Bs[cur][((wc * 96 + j * 16 + lane15) * 4 + quad) * 8];
        __builtin_amdgcn_s_setprio(1);
        #pragma unroll
        for (int i = 0; i < 4; ++i)
            #pragma unroll
            for (int j = 0; j < 6; ++j)
                acc[i][j] = __builtin_amdgcn_mfma_f32_16x16x32_bf16(af[i], bf[j], acc[i][j], 0, 0, 0);
        __builtin_amdgcn_s_setprio(0);
        __syncthreads();
        cur ^= 1;
    }

    // coalesced: lane15 -> consecutive k; 16-lane group = 32B contiguous
    #pragma unroll
    for (int i = 0; i < 4; ++i) {
        #pragma unroll
        for (int j = 0; j < 6; ++j) {
            int k = wc * 96 + j * 16 + lane15;
            #pragma unroll
            for (int e = 0; e < 4; ++e) {
                int cr = c0 + wr * 64 + i * 16 + quad * 4 + e;
                xsT[((size_t)m * CR + cr) * KTP + k] = f2bf(acc[i][j][e]);
            }
        }
    }
}

// ---------------------------------------------------------------------------
// xsT bf16 [m][cr][KTP] -> xs bf16 [ck][MRP]; both sides coalesced via LDS.
__global__ __launch_bounds__(256)
void sht_xs_tr(const unsigned short* __restrict__ xsT, unsigned short* __restrict__ xs) {
    __shared__ unsigned short tile[128 * 65];
    const int c  = blockIdx.y;          // 0..127
    const int bx = blockIdx.x;          // 0..35
    const int mt = bx / 6, kt = bx % 6;
    const int m0 = mt * 64, k0 = kt * 64;
    const int t  = threadIdx.x;

    #pragma unroll
    for (int u = 0; u < 4; ++u) {
        int q = t + 256 * u;
        int rho = q >> 3, ko8 = q & 7;
        int mi = rho >> 1, r = rho & 1;
        int m = m0 + mi;
        short8 v = {};
        if (m < MDIM)
            v = *(const short8*)(xsT + ((size_t)m * CR + 2 * c + r) * KTP + k0 + ko8 * 8);
        *(short8*)&tile[rho * 65 + ko8 * 8] = v;
    }
    __syncthreads();

    #pragma unroll
    for (int u = 0; u < 4; ++u) {
        int q = t + 256 * u;
        int kk = q >> 4, mc = q & 15;
        int k = k0 + kk;
        int mr0 = 2 * m0 + mc * 8;
        if (k >= KDIM || mr0 >= MRP) continue;
        short8 h;
        #pragma unroll
        for (int e = 0; e < 8; ++e)
            h[e] = (short)tile[(mc * 8 + e) * 65 + kk];
        *(short8*)(xs + (size_t)(c * KDIM + k) * MRP + mr0) = h;
    }
}

// ---------------------------------------------------------------------------
// Stage A2 (fast1): scatter epilogue direct to xs (round-3 measured, 148us).
__global__ __launch_bounds__(512)
void sht_stageA2(const unsigned short* __restrict__ pctT, const unsigned short* __restrict__ xA,
                 unsigned short* __restrict__ xs) {
    __shared__ unsigned short As[128 * 32];
    __shared__ unsigned short Bs[384 * 32];

    const int p   = xcd_swz(blockIdx.x, 2 * MDIM);
    const int m   = p >> 1, ct = p & 1;
    const int c0  = ct * 128;
    const int t   = threadIdx.x;
    const int w   = t >> 6, L = t & 63;
    const int wr  = w & 1, wc = w >> 1;
    const int lane15 = L & 15, quad = L >> 4;
    const int arr = t >> 2, alq = t & 3;

    const unsigned short* xAm = xA + (size_t)m * CR * LP;
    const unsigned short* pTm = pctT + (size_t)m * KP * LP;

    floatx4 acc[4][6] = {};

    for (int kb = 0; kb < LP; kb += 32) {
        async_copy16(xAm + (size_t)(c0 + arr) * LP + kb + alq * 8,
                     As + (size_t)(w * 64) * 8);
        #pragma unroll
        for (int u = 0; u < 3; ++u) {
            int s = u * 512 + t;
            int rr = s >> 2, lq = s & 3;
            async_copy16(pTm + (size_t)rr * LP + kb + lq * 8,
                         Bs + (size_t)(u * 512 + w * 64) * 8);
        }
        __syncthreads();

        short8 af[4], bf[6];
        #pragma unroll
        for (int i = 0; i < 4; ++i)
            af[i] = *(const short8*)&As[((wr * 64 + i * 16 + lane15) * 4 + quad) * 8];
        #pragma unroll
        for (int j = 0; j < 6; ++j)
            bf[j] = *(const short8*)&Bs[((wc * 96 + j * 16 + lane15) * 4 + quad) * 8];
        #pragma unroll
        for (int i = 0; i < 4; ++i)
            #pragma unroll
            for (int j = 0; j < 6; ++j)
                acc[i][j] = __builtin_amdgcn_mfma_f32_16x16x32_bf16(af[i], bf[j], acc[i][j], 0, 0, 0);
        __syncthreads();
    }

    #pragma unroll
    for (int j = 0; j < 6; ++j) {
        int k = wc * 96 + j * 16 + lane15;
        if (k >= KDIM) continue;
        #pragma unroll
        for (int i = 0; i < 4; ++i) {
            #pragma unroll
            for (int eh = 0; eh < 2; ++eh) {
                int cr = c0 + wr * 64 + i * 16 + quad * 4 + eh * 2;
                int c  = cr >> 1;
                unsigned pack = (unsigned)f2bf(acc[i][j][eh * 2]) |
                                ((unsigned)f2bf(acc[i][j][eh * 2 + 1]) << 16);
                *(unsigned*)(xs + (size_t)(c * KDIM + k) * MRP + 2 * m) = pack;
            }
        }
    }
}

// ---------------------------------------------------------------------------
// Stage A (tier0 fallback): original in-loop fp32 pct staging.
__global__ __launch_bounds__(256)
void sht_stageA(const float* __restrict__ pct, const unsigned short* __restrict__ xA,
                unsigned short* __restrict__ xs) {
    __shared__ unsigned short As[128 * 32];
    __shared__ unsigned short Bs[32 * 130];

    const int m   = blockIdx.y;
    const int ct  = blockIdx.x & 1;
    const int kt  = blockIdx.x >> 1;
    const int c0  = ct * 128;
    const int n0  = kt * 128;
    const int t   = threadIdx.x;
    const int w   = t >> 6, L = t & 63;
    const int wr  = w & 1, wc = w >> 1;
    const int lane15 = L & 15, quad = L >> 4;
    const int bl = t >> 3, bkq = t & 7;

    const unsigned short* xAm = xA + (size_t)m * CR * LP;
    const float* pctm = pct + (size_t)m * LDIM * KDIM;

    floatx4 acc[4][4] = {};

    for (int kb = 0; kb < LP; kb += 32) {
        #pragma unroll
        for (int i = 0; i < 2; ++i) {
            int s = w * 128 + i * 64 + L;
            int cr = s >> 2, lq = s & 3;
            async_copy16(xAm + (size_t)(c0 + cr) * LP + kb + lq * 8,
                         As + (size_t)(w * 128 + i * 64) * 8);
        }
        {
            int l = kb + bl;
            bool lok = (l < LDIM);
            const float* prow = pctm + (size_t)l * KDIM;
            #pragma unroll
            for (int u = 0; u < 4; ++u) {
                int kc = n0 + u * 32 + bkq * 4;
                float f0 = (lok && kc + 0 < KDIM) ? prow[kc + 0] : 0.f;
                float f1 = (lok && kc + 1 < KDIM) ? prow[kc + 1] : 0.f;
                float f2 = (lok && kc + 2 < KDIM) ? prow[kc + 2] : 0.f;
                float f3 = (lok && kc + 3 < KDIM) ? prow[kc + 3] : 0.f;
                unsigned* bp = (unsigned*)&Bs[bl * 130 + u * 32 + bkq * 4];
                bp[0] = (unsigned)f2bf(f0) | ((unsigned)f2bf(f1) << 16);
                bp[1] = (unsigned)f2bf(f2) | ((unsigned)f2bf(f3) << 16);
            }
        }
        __syncthreads();

        short8 af[4];
        #pragma unroll
        for (int i = 0; i < 4; ++i) {
            int row = wr * 64 + i * 16 + lane15;
            af[i] = *(const short8*)&As[(row * 4 + quad) * 8];
        }
        #pragma unroll
        for (int jf = 0; jf < 4; ++jf) {
            int col = wc * 64 + jf * 16 + lane15;
            short8 bf;
            #pragma unroll
            for (int j = 0; j < 8; ++j)
                bf[j] = (short)Bs[(quad * 8 + j) * 130 + col];
            #pragma unroll
            for (int i = 0; i < 4; ++i)
                acc[i][jf] = __builtin_amdgcn_mfma_f32_16x16x32_bf16(af[i], bf, acc[i][jf], 0, 0, 0);
        }
        __syncthreads();
    }

    #pragma unroll
    for (int i = 0; i < 4; ++i) {
        #pragma unroll
        for (int jf = 0; jf < 4; ++jf) {
            int k = n0 + wc * 64 + jf * 16 + lane15;
            if (k >= KDIM) continue;
            #pragma unroll
            for (int eh = 0; eh < 2; ++eh) {
                int cr = c0 + wr * 64 + i * 16 + quad * 4 + eh * 2;
                int c  = cr >> 1;
                unsigned pack = (unsigned)f2bf(acc[i][jf][eh * 2]) |
                                ((unsigned)f2bf(acc[i][jf][eh * 2 + 1]) << 16);
                *(unsigned*)(xs + (size_t)(c * KDIM + k) * MRP + 2 * m) = pack;
            }
        }
    }
}

// ---------------------------------------------------------------------------
// Stage B3: out[ck][j] = sum_mr xs[ck][mr] * Tp[j][mr]
// Double-buffered 2-phase (same schedule as A4).
__global__ __launch_bounds__(512)
void sht_stageB3(const unsigned short* __restrict__ xs, const unsigned short* __restrict__ Tp,
                 float* __restrict__ out) {
    __shared__ unsigned short As[2][128 * 32];   // 16 KB
    __shared__ unsigned short Bs[2][384 * 32];   // 48 KB

    const int p   = xcd_swz(blockIdx.x, 2 * MDIM);
    const int ckt = p >> 1, nt = p & 1;
    const int ck0 = ckt * 128, n0 = nt * 384;
    const int t   = threadIdx.x;
    const int w   = t >> 6, L = t & 63;
    const int wr  = w & 1, wc = w >> 1;
    const int lane15 = L & 15, quad = L >> 4;
    const int arr = t >> 2, alq = t & 3;

    floatx4 acc[4][6] = {};

    auto stage = [&](int buf, int kb) {
        async_copy16(xs + (size_t)(ck0 + arr) * MRP + kb + alq * 8,
                     &As[buf][(w * 64) * 8]);
        #pragma unroll
        for (int u = 0; u < 3; ++u) {
            int s = u * 512 + t;
            int rr = s >> 2, lq = s & 3;
            async_copy16(Tp + (size_t)(n0 + rr) * MRP + kb + lq * 8,
                         &Bs[buf][(u * 512 + w * 64) * 8]);
        }
    };

    const int NT = MRP / 32;   // 23
    stage(0, 0);
    __syncthreads();

    int cur = 0;
    for (int it = 0; it < NT; ++it) {
        if (it + 1 < NT) stage(cur ^ 1, (it + 1) * 32);

        short8 af[4], bf[6];
        #pragma unroll
        for (int i = 0; i < 4; ++i)
            af[i] = *(const short8*)&As[cur][((wr * 64 + i * 16 + lane15) * 4 + quad) * 8];
        #pragma unroll
        for (int j = 0; j < 6; ++j)
            bf[j] = *(const short8*)&Bs[cur][((wc * 96 + j * 16 + lane15) * 4 + quad) * 8];
        __builtin_amdgcn_s_setprio(1);
        #pragma unroll
        for (int i = 0; i < 4; ++i)
            #pragma unroll
            for (int j = 0; j < 6; ++j)
                acc[i][j] = __builtin_amdgcn_mfma_f32_16x16x32_bf16(af[i], bf[j], acc[i][j], 0, 0, 0);
        __builtin_amdgcn_s_setprio(0);
        __syncthreads();
        cur ^= 1;
    }

    #pragma unroll
    for (int i = 0; i < 4; ++i) {
        int ckr = ck0 + wr * 64 + i * 16 + quad * 4;
        #pragma unroll
        for (int j = 0; j < 6; ++j) {
            int jj = n0 + wc * 96 + j * 16 + lane15;
            if (jj >= NLON) continue;
            #pragma unroll
            for (int e = 0; e < 4; ++e)
                out[(size_t)(ckr + e) * NLON + jj] = acc[i][j][e];
        }
    }
}

// ---------------------------------------------------------------------------
extern "C" void kernel_launch(void* const* d_in, const int* in_sizes, int n_in,
                              void* d_out, int out_size, void* d_ws, size_t ws_size,
                              hipStream_t stream) {
    const float* x   = (const float*)d_in[0];   // [1,128,361,361,2] fp32
    const float* pct = (const float*)d_in[1];   // [361,361,361] fp32
    float* out = (float*)d_out;                 // [1,128,361,720] fp32

    unsigned short* xs = (unsigned short*)d_ws;              // CK*MRP (68.0 MB)
    unsigned short* Tp = xs + (size_t)CK * MRP;              // NP*MRP (1.13 MB)
    unsigned short* xA = (unsigned short*)d_out;             // dead before stage B

    const size_t base_shorts = (size_t)CK * MRP + (size_t)NP * MRP;
    const size_t pctT_shorts = (size_t)MDIM * KP * LP;       // 106.5 MB
    const size_t xsT_shorts  = (size_t)MDIM * CR * KTP;      // 71.0 MB
    const bool fast1 = ws_size >= (base_shorts + pctT_shorts) * sizeof(unsigned short);
    const bool fast2 = ws_size >= (base_shorts + pctT_shorts + xsT_shorts) * sizeof(unsigned short);

    sht_gen_T<<<(NP * MRP + 255) / 256, 256, 0, stream>>>(Tp);
    sht_prep_x<<<dim3(12, 6, 128), 256, 0, stream>>>(x, xA);
    if (fast2) {
        unsigned short* pctT = Tp + (size_t)NP * MRP;
        unsigned short* xsT  = pctT + pctT_shorts;
        sht_prep_pct<<<dim3(144, MDIM), 256, 0, stream>>>(pct, pctT);
        sht_stageA4<<<dim3(2 * MDIM), 512, 0, stream>>>(pctT, xA, xsT);
        sht_xs_tr<<<dim3(36, 128), 256, 0, stream>>>(xsT, xs);
    } else if (fast1) {
        unsigned short* pctT = Tp + (size_t)NP * MRP;
        sht_prep_pct<<<dim3(144, MDIM), 256, 0, stream>>>(pct, pctT);
        sht_stageA2<<<dim3(2 * MDIM), 512, 0, stream>>>(pctT, xA, xs);
    } else {
        sht_stageA<<<dim3(6, MDIM), 256, 0, stream>>>(pct, xA, xs);
    }
    sht_stageB3<<<dim3(2 * MDIM), 512, 0, stream>>>(xs, Tp, out);
}

// Round 6
// 601.464 us; speedup vs baseline: 1.2079x; 1.0420x over previous
//
#include <hip/hip_runtime.h>
#include <cstddef>

#define CC   128
#define LDIM 361
#define MDIM 361
#define KDIM 361
#define NLON 720
#define LP   384          // padded l (stage A K-dim)
#define KP   384          // padded k rows for pctT
#define KTP  384          // xsT row stride (k-contiguous)
#define MRP  736          // padded mr (stage B K-dim)
#define NP   768          // padded n (stage B N-dim)
#define CK   (CC*KDIM)    // 46208
#define CR   (2*CC)       // 256

typedef __attribute__((ext_vector_type(8))) short short8;
typedef __attribute__((ext_vector_type(4))) float floatx4;

__device__ __forceinline__ unsigned short f2bf(float f) {
    union { float f; unsigned u; } v; v.f = f;
    unsigned u = v.u;
    u += 0x7fffu + ((u >> 16) & 1u);   // RNE
    return (unsigned short)(u >> 16);
}

__device__ __forceinline__ void async_copy16(const void* g, void* l) {
    __builtin_amdgcn_global_load_lds(
        (const __attribute__((address_space(1))) void*)g,
        (__attribute__((address_space(3))) void*)l, 16, 0, 0);
}

// Bijective XCD-chunk swizzle (m204).
__device__ __forceinline__ int xcd_swz(int id, int P) {
    int x = id & 7, g = id >> 3;
    int q = P >> 3, r = P & 7;
    int start = (x < r) ? x * (q + 1) : r * (q + 1) + (x - r) * q;
    return start + g;
}

// ---------------------------------------------------------------------------
// Tp[n][mr] bf16, n<720 & mr<722 real weights, else 0 (pad kills xs poison).
__global__ void sht_gen_T(unsigned short* __restrict__ Tp) {
    int idx = blockIdx.x * 256 + threadIdx.x;
    if (idx >= NP * MRP) return;
    int n = idx / MRP, mr = idx - n * MRP;
    float v = 0.f;
    if (n < NLON && mr < 2 * MDIM) {
        int m = mr >> 1, im = mr & 1;
        if (m == 0)            v = im ? 0.f : 1.f;
        else if (m == MDIM-1)  v = im ? 0.f : ((n & 1) ? -1.f : 1.f);
        else {
            int ph = (m * n) % NLON;
            float ang = (float)ph * (float)(3.14159265358979323846 / 360.0);
            v = im ? (-2.f * sinf(ang)) : (2.f * cosf(ang));
        }
    }
    Tp[idx] = f2bf(v);
}

// ---------------------------------------------------------------------------
// x fp32 [c][l][m][r] -> xA bf16 [m][cr=2c+r][LP]  (l-fast, zero pad l>=361)
// m-major LDS planes (stride 65, +4-word skew): store banks (mi+li)%32 all
// distinct; read banks (mi+lo+e+4rr)%32 exactly 2-way -> conflict-free.
__global__ __launch_bounds__(256)
void sht_prep_x(const float* __restrict__ x, unsigned short* __restrict__ xA) {
    __shared__ float tp[2][32 * 65 + 4];
    const int mt = blockIdx.x;         // 0..11
    const int lt = blockIdx.y;         // 0..5
    const int c  = blockIdx.z;         // 0..127
    const int t  = threadIdx.x;

    #pragma unroll
    for (int u = 0; u < 8; ++u) {
        int p  = t + 256 * u;
        int li = p >> 5, mi = p & 31;
        int l = lt * 64 + li, m = mt * 32 + mi;
        float2 v = make_float2(0.f, 0.f);
        if (l < LDIM && m < MDIM)
            v = *(const float2*)(x + ((size_t)(c * LDIM + l) * MDIM + m) * 2);
        tp[0][mi * 65 + li] = v.x;
        tp[1][mi * 65 + li] = v.y;
    }
    __syncthreads();

    #pragma unroll
    for (int u = 0; u < 2; ++u) {
        int s  = t + 256 * u;          // 0..511
        int mi = s >> 4, rr = (s >> 3) & 1, lo = (s & 7) * 8;
        int m = mt * 32 + mi;
        if (m >= MDIM) continue;
        const float* pl = &tp[rr][mi * 65];
        short8 h;
        #pragma unroll
        for (int e = 0; e < 8; ++e)
            h[e] = (short)f2bf(pl[lo + e]);
        *(short8*)(xA + ((size_t)m * CR + 2 * c + rr) * LP + lt * 64 + lo) = h;
    }
}

// ---------------------------------------------------------------------------
// pct fp32 [m][l][k] -> pctT bf16 [m][k][LP]  (round-1 measured version)
__global__ __launch_bounds__(256)
void sht_prep_pct(const float* __restrict__ pct, unsigned short* __restrict__ pctT) {
    __shared__ float tile[32][33];
    const int m  = blockIdx.y;
    const int kt = blockIdx.x % 12;
    const int lt = blockIdx.x / 12;
    const int l0 = lt * 32, k0 = kt * 32;
    const int t  = threadIdx.x;

    const int ki = t & 31, lbase = t >> 5;
    #pragma unroll
    for (int u = 0; u < 4; ++u) {
        int li = lbase + 8 * u;
        int l = l0 + li, k = k0 + ki;
        float v = 0.f;
        if (l < LDIM && k < KDIM)
            v = pct[((size_t)m * LDIM + l) * KDIM + k];
        tile[li][ki] = v;
    }
    __syncthreads();

    const int ko = t >> 3, lo = (t & 7) * 4;
    unsigned pk0 = (unsigned)f2bf(tile[lo + 0][ko]) | ((unsigned)f2bf(tile[lo + 1][ko]) << 16);
    unsigned pk1 = (unsigned)f2bf(tile[lo + 2][ko]) | ((unsigned)f2bf(tile[lo + 3][ko]) << 16);
    unsigned* dst = (unsigned*)(pctT + ((size_t)m * KP + k0 + ko) * LP + l0 + lo);
    dst[0] = pk0; dst[1] = pk1;
}

// ---------------------------------------------------------------------------
// Stage A5: per-m GEMM, 3-buffer ring + counted vmcnt (T4). Coalesced xsT out.
__global__ __launch_bounds__(512)
void sht_stageA5(const unsigned short* __restrict__ pctT, const unsigned short* __restrict__ xA,
                 unsigned short* __restrict__ xsT) {
    __shared__ unsigned short As[3][128 * 32];   // 24 KB
    __shared__ unsigned short Bs[3][384 * 32];   // 72 KB

    const int p   = xcd_swz(blockIdx.x, 2 * MDIM);
    const int m   = p >> 1, ct = p & 1;
    const int c0  = ct * 128;
    const int t   = threadIdx.x;
    const int w   = t >> 6, L = t & 63;
    const int wr  = w & 1, wc = w >> 1;
    const int lane15 = L & 15, quad = L >> 4;
    const int arr = t >> 2, alq = t & 3;

    const unsigned short* xAm = xA + (size_t)m * CR * LP;
    const unsigned short* pTm = pctT + (size_t)m * KP * LP;

    floatx4 acc[4][6] = {};

    auto stage = [&](int buf, int kb) {
        async_copy16(xAm + (size_t)(c0 + arr) * LP + kb + alq * 8,
                     &As[buf][(w * 64) * 8]);
        #pragma unroll
        for (int u = 0; u < 3; ++u) {
            int s = u * 512 + t;
            int rr = s >> 2, lq = s & 3;
            async_copy16(pTm + (size_t)rr * LP + kb + lq * 8,
                         &Bs[buf][(u * 512 + w * 64) * 8]);
        }
    };

    const int NT = LP / 32;    // 12
    stage(0, 0);
    stage(1, 32);

    for (int it = 0; it < NT; ++it) {
        const int cb = it % 3;
        if (it + 1 < NT) { asm volatile("s_waitcnt vmcnt(4)" ::: "memory"); }
        else             { asm volatile("s_waitcnt vmcnt(0)" ::: "memory"); }
        __builtin_amdgcn_sched_barrier(0);
        __builtin_amdgcn_s_barrier();
        __builtin_amdgcn_sched_barrier(0);

        short8 af[4], bf[6];
        #pragma unroll
        for (int i = 0; i < 4; ++i)
            af[i] = *(const short8*)&As[cb][((wr * 64 + i * 16 + lane15) * 4 + quad) * 8];
        #pragma unroll
        for (int j = 0; j < 6; ++j)
            bf[j] = *(const short8*)&Bs[cb][((wc * 96 + j * 16 + lane15) * 4 + quad) * 8];
        __builtin_amdgcn_s_setprio(1);
        #pragma unroll
        for (int i = 0; i < 4; ++i)
            #pragma unroll
            for (int j = 0; j < 6; ++j)
                acc[i][j] = __builtin_amdgcn_mfma_f32_16x16x32_bf16(af[i], bf[j], acc[i][j], 0, 0, 0);
        __builtin_amdgcn_s_setprio(0);

        if (it + 2 < NT) stage((it + 2) % 3, (it + 2) * 32);
    }

    // coalesced: lane15 -> consecutive k; 16-lane group = 32B contiguous
    #pragma unroll
    for (int i = 0; i < 4; ++i) {
        #pragma unroll
        for (int j = 0; j < 6; ++j) {
            int k = wc * 96 + j * 16 + lane15;
            #pragma unroll
            for (int e = 0; e < 4; ++e) {
                int cr = c0 + wr * 64 + i * 16 + quad * 4 + e;
                xsT[((size_t)m * CR + cr) * KTP + k] = f2bf(acc[i][j][e]);
            }
        }
    }
}

// ---------------------------------------------------------------------------
// xsT bf16 [m][cr][KTP] -> xs bf16 [ck][MRP]; u32-pack transpose, <=2-way banks.
__global__ __launch_bounds__(256)
void sht_xs_tr(const unsigned short* __restrict__ xsT, unsigned short* __restrict__ xs) {
    __shared__ unsigned tile32[64 * 65];   // [k][mi] u32 = (bf16 r0 | r1<<16), 16.6KB
    const int c  = blockIdx.y;          // 0..127
    const int bx = blockIdx.x;          // 0..35
    const int mt = bx / 6, kt = bx % 6;
    const int m0 = mt * 64, k0 = kt * 64;
    const int t  = threadIdx.x;

    // phase 1: 512 tasks; task q: mi=q>>3 (0..63), ko8=q&7. Pack r0/r1 -> u32.
    #pragma unroll
    for (int u = 0; u < 2; ++u) {
        int q  = t + 256 * u;
        int mi = q >> 3, ko8 = q & 7;
        int m  = m0 + mi;
        short8 a = {}, b = {};
        if (m < MDIM) {
            const unsigned short* base = xsT + ((size_t)m * CR + 2 * c) * KTP + k0 + ko8 * 8;
            a = *(const short8*)base;
            b = *(const short8*)(base + KTP);
        }
        #pragma unroll
        for (int e = 0; e < 8; ++e)
            tile32[(ko8 * 8 + e) * 65 + mi] =
                (unsigned)(unsigned short)a[e] | ((unsigned)(unsigned short)b[e] << 16);
    }
    __syncthreads();

    // phase 2: 1024 tasks; task q: kk=q>>4 (0..63), mc=q&15. 4 u32 -> 16B store.
    #pragma unroll
    for (int u = 0; u < 4; ++u) {
        int q  = t + 256 * u;
        int kk = q >> 4, mc = q & 15;
        int k  = k0 + kk;
        int mr0 = 2 * m0 + mc * 8;
        if (k >= KDIM || mr0 >= MRP) continue;
        unsigned w0 = tile32[kk * 65 + mc * 4 + 0];
        unsigned w1 = tile32[kk * 65 + mc * 4 + 1];
        unsigned w2 = tile32[kk * 65 + mc * 4 + 2];
        unsigned w3 = tile32[kk * 65 + mc * 4 + 3];
        unsigned* dst = (unsigned*)(xs + (size_t)(c * KDIM + k) * MRP + mr0);
        dst[0] = w0; dst[1] = w1; dst[2] = w2; dst[3] = w3;
    }
}

// ---------------------------------------------------------------------------
// Stage A2 (fast1 fallback): scatter epilogue direct to xs (round-3, 148us).
__global__ __launch_bounds__(512)
void sht_stageA2(const unsigned short* __restrict__ pctT, const unsigned short* __restrict__ xA,
                 unsigned short* __restrict__ xs) {
    __shared__ unsigned short As[128 * 32];
    __shared__ unsigned short Bs[384 * 32];

    const int p   = xcd_swz(blockIdx.x, 2 * MDIM);
    const int m   = p >> 1, ct = p & 1;
    const int c0  = ct * 128;
    const int t   = threadIdx.x;
    const int w   = t >> 6, L = t & 63;
    const int wr  = w & 1, wc = w >> 1;
    const int lane15 = L & 15, quad = L >> 4;
    const int arr = t >> 2, alq = t & 3;

    const unsigned short* xAm = xA + (size_t)m * CR * LP;
    const unsigned short* pTm = pctT + (size_t)m * KP * LP;

    floatx4 acc[4][6] = {};

    for (int kb = 0; kb < LP; kb += 32) {
        async_copy16(xAm + (size_t)(c0 + arr) * LP + kb + alq * 8,
                     As + (size_t)(w * 64) * 8);
        #pragma unroll
        for (int u = 0; u < 3; ++u) {
            int s = u * 512 + t;
            int rr = s >> 2, lq = s & 3;
            async_copy16(pTm + (size_t)rr * LP + kb + lq * 8,
                         Bs + (size_t)(u * 512 + w * 64) * 8);
        }
        __syncthreads();

        short8 af[4], bf[6];
        #pragma unroll
        for (int i = 0; i < 4; ++i)
            af[i] = *(const short8*)&As[((wr * 64 + i * 16 + lane15) * 4 + quad) * 8];
        #pragma unroll
        for (int j = 0; j < 6; ++j)
            bf[j] = *(const short8*)&Bs[((wc * 96 + j * 16 + lane15) * 4 + quad) * 8];
        #pragma unroll
        for (int i = 0; i < 4; ++i)
            #pragma unroll
            for (int j = 0; j < 6; ++j)
                acc[i][j] = __builtin_amdgcn_mfma_f32_16x16x32_bf16(af[i], bf[j], acc[i][j], 0, 0, 0);
        __syncthreads();
    }

    #pragma unroll
    for (int j = 0; j < 6; ++j) {
        int k = wc * 96 + j * 16 + lane15;
        if (k >= KDIM) continue;
        #pragma unroll
        for (int i = 0; i < 4; ++i) {
            #pragma unroll
            for (int eh = 0; eh < 2; ++eh) {
                int cr = c0 + wr * 64 + i * 16 + quad * 4 + eh * 2;
                int c  = cr >> 1;
                unsigned pack = (unsigned)f2bf(acc[i][j][eh * 2]) |
                                ((unsigned)f2bf(acc[i][j][eh * 2 + 1]) << 16);
                *(unsigned*)(xs + (size_t)(c * KDIM + k) * MRP + 2 * m) = pack;
            }
        }
    }
}

// ---------------------------------------------------------------------------
// Stage A (tier0 fallback): original in-loop fp32 pct staging.
__global__ __launch_bounds__(256)
void sht_stageA(const float* __restrict__ pct, const unsigned short* __restrict__ xA,
                unsigned short* __restrict__ xs) {
    __shared__ unsigned short As[128 * 32];
    __shared__ unsigned short Bs[32 * 130];

    const int m   = blockIdx.y;
    const int ct  = blockIdx.x & 1;
    const int kt  = blockIdx.x >> 1;
    const int c0  = ct * 128;
    const int n0  = kt * 128;
    const int t   = threadIdx.x;
    const int w   = t >> 6, L = t & 63;
    const int wr  = w & 1, wc = w >> 1;
    const int lane15 = L & 15, quad = L >> 4;
    const int bl = t >> 3, bkq = t & 7;

    const unsigned short* xAm = xA + (size_t)m * CR * LP;
    const float* pctm = pct + (size_t)m * LDIM * KDIM;

    floatx4 acc[4][4] = {};

    for (int kb = 0; kb < LP; kb += 32) {
        #pragma unroll
        for (int i = 0; i < 2; ++i) {
            int s = w * 128 + i * 64 + L;
            int cr = s >> 2, lq = s & 3;
            async_copy16(xAm + (size_t)(c0 + cr) * LP + kb + lq * 8,
                         As + (size_t)(w * 128 + i * 64) * 8);
        }
        {
            int l = kb + bl;
            bool lok = (l < LDIM);
            const float* prow = pctm + (size_t)l * KDIM;
            #pragma unroll
            for (int u = 0; u < 4; ++u) {
                int kc = n0 + u * 32 + bkq * 4;
                float f0 = (lok && kc + 0 < KDIM) ? prow[kc + 0] : 0.f;
                float f1 = (lok && kc + 1 < KDIM) ? prow[kc + 1] : 0.f;
                float f2 = (lok && kc + 2 < KDIM) ? prow[kc + 2] : 0.f;
                float f3 = (lok && kc + 3 < KDIM) ? prow[kc + 3] : 0.f;
                unsigned* bp = (unsigned*)&Bs[bl * 130 + u * 32 + bkq * 4];
                bp[0] = (unsigned)f2bf(f0) | ((unsigned)f2bf(f1) << 16);
                bp[1] = (unsigned)f2bf(f2) | ((unsigned)f2bf(f3) << 16);
            }
        }
        __syncthreads();

        short8 af[4];
        #pragma unroll
        for (int i = 0; i < 4; ++i) {
            int row = wr * 64 + i * 16 + lane15;
            af[i] = *(const short8*)&As[(row * 4 + quad) * 8];
        }
        #pragma unroll
        for (int jf = 0; jf < 4; ++jf) {
            int col = wc * 64 + jf * 16 + lane15;
            short8 bf;
            #pragma unroll
            for (int j = 0; j < 8; ++j)
                bf[j] = (short)Bs[(quad * 8 + j) * 130 + col];
            #pragma unroll
            for (int i = 0; i < 4; ++i)
                acc[i][jf] = __builtin_amdgcn_mfma_f32_16x16x32_bf16(af[i], bf, acc[i][jf], 0, 0, 0);
        }
        __syncthreads();
    }

    #pragma unroll
    for (int i = 0; i < 4; ++i) {
        #pragma unroll
        for (int jf = 0; jf < 4; ++jf) {
            int k = n0 + wc * 64 + jf * 16 + lane15;
            if (k >= KDIM) continue;
            #pragma unroll
            for (int eh = 0; eh < 2; ++eh) {
                int cr = c0 + wr * 64 + i * 16 + quad * 4 + eh * 2;
                int c  = cr >> 1;
                unsigned pack = (unsigned)f2bf(acc[i][jf][eh * 2]) |
                                ((unsigned)f2bf(acc[i][jf][eh * 2 + 1]) << 16);
                *(unsigned*)(xs + (size_t)(c * KDIM + k) * MRP + 2 * m) = pack;
            }
        }
    }
}

// ---------------------------------------------------------------------------
// Stage B4: out[ck][j] = sum_mr xs[ck][mr] * Tp[j][mr]
// 3-buffer ring + counted vmcnt (T4), same tile structure as B3.
__global__ __launch_bounds__(512)
void sht_stageB4(const unsigned short* __restrict__ xs, const unsigned short* __restrict__ Tp,
                 float* __restrict__ out) {
    __shared__ unsigned short As[3][128 * 32];   // 24 KB
    __shared__ unsigned short Bs[3][384 * 32];   // 72 KB

    const int p   = xcd_swz(blockIdx.x, 2 * MDIM);
    const int ckt = p >> 1, nt = p & 1;
    const int ck0 = ckt * 128, n0 = nt * 384;
    const int t   = threadIdx.x;
    const int w   = t >> 6, L = t & 63;
    const int wr  = w & 1, wc = w >> 1;
    const int lane15 = L & 15, quad = L >> 4;
    const int arr = t >> 2, alq = t & 3;

    floatx4 acc[4][6] = {};

    auto stage = [&](int buf, int kb) {
        async_copy16(xs + (size_t)(ck0 + arr) * MRP + kb + alq * 8,
                     &As[buf][(w * 64) * 8]);
        #pragma unroll
        for (int u = 0; u < 3; ++u) {
            int s = u * 512 + t;
            int rr = s >> 2, lq = s & 3;
            async_copy16(Tp + (size_t)(n0 + rr) * MRP + kb + lq * 8,
                         &Bs[buf][(u * 512 + w * 64) * 8]);
        }
    };

    const int NT = MRP / 32;   // 23
    stage(0, 0);
    stage(1, 32);

    for (int it = 0; it < NT; ++it) {
        const int cb = it % 3;
        if (it + 1 < NT) { asm volatile("s_waitcnt vmcnt(4)" ::: "memory"); }
        else             { asm volatile("s_waitcnt vmcnt(0)" ::: "memory"); }
        __builtin_amdgcn_sched_barrier(0);
        __builtin_amdgcn_s_barrier();
        __builtin_amdgcn_sched_barrier(0);

        short8 af[4], bf[6];
        #pragma unroll
        for (int i = 0; i < 4; ++i)
            af[i] = *(const short8*)&As[cb][((wr * 64 + i * 16 + lane15) * 4 + quad) * 8];
        #pragma unroll
        for (int j = 0; j < 6; ++j)
            bf[j] = *(const short8*)&Bs[cb][((wc * 96 + j * 16 + lane15) * 4 + quad) * 8];
        __builtin_amdgcn_s_setprio(1);
        #pragma unroll
        for (int i = 0; i < 4; ++i)
            #pragma unroll
            for (int j = 0; j < 6; ++j)
                acc[i][j] = __builtin_amdgcn_mfma_f32_16x16x32_bf16(af[i], bf[j], acc[i][j], 0, 0, 0);
        __builtin_amdgcn_s_setprio(0);

        if (it + 2 < NT) stage((it + 2) % 3, (it + 2) * 32);
    }

    #pragma unroll
    for (int i = 0; i < 4; ++i) {
        int ckr = ck0 + wr * 64 + i * 16 + quad * 4;
        #pragma unroll
        for (int j = 0; j < 6; ++j) {
            int jj = n0 + wc * 96 + j * 16 + lane15;
            if (jj >= NLON) continue;
            #pragma unroll
            for (int e = 0; e < 4; ++e)
                out[(size_t)(ckr + e) * NLON + jj] = acc[i][j][e];
        }
    }
}

// ---------------------------------------------------------------------------
extern "C" void kernel_launch(void* const* d_in, const int* in_sizes, int n_in,
                              void* d_out, int out_size, void* d_ws, size_t ws_size,
                              hipStream_t stream) {
    const float* x   = (const float*)d_in[0];   // [1,128,361,361,2] fp32
    const float* pct = (const float*)d_in[1];   // [361,361,361] fp32
    float* out = (float*)d_out;                 // [1,128,361,720] fp32

    unsigned short* xs = (unsigned short*)d_ws;              // CK*MRP (68.0 MB)
    unsigned short* Tp = xs + (size_t)CK * MRP;              // NP*MRP (1.13 MB)
    unsigned short* xA = (unsigned short*)d_out;             // dead before stage B

    const size_t base_shorts = (size_t)CK * MRP + (size_t)NP * MRP;
    const size_t pctT_shorts = (size_t)MDIM * KP * LP;       // 106.5 MB
    const size_t xsT_shorts  = (size_t)MDIM * CR * KTP;      // 71.0 MB
    const bool fast1 = ws_size >= (base_shorts + pctT_shorts) * sizeof(unsigned short);
    const bool fast2 = ws_size >= (base_shorts + pctT_shorts + xsT_shorts) * sizeof(unsigned short);

    sht_gen_T<<<(NP * MRP + 255) / 256, 256, 0, stream>>>(Tp);
    sht_prep_x<<<dim3(12, 6, 128), 256, 0, stream>>>(x, xA);
    if (fast2) {
        unsigned short* pctT = Tp + (size_t)NP * MRP;
        unsigned short* xsT  = pctT + pctT_shorts;
        sht_prep_pct<<<dim3(144, MDIM), 256, 0, stream>>>(pct, pctT);
        sht_stageA5<<<dim3(2 * MDIM), 512, 0, stream>>>(pctT, xA, xsT);
        sht_xs_tr<<<dim3(36, 128), 256, 0, stream>>>(xsT, xs);
    } else if (fast1) {
        unsigned short* pctT = Tp + (size_t)NP * MRP;
        sht_prep_pct<<<dim3(144, MDIM), 256, 0, stream>>>(pct, pctT);
        sht_stageA2<<<dim3(2 * MDIM), 512, 0, stream>>>(pctT, xA, xs);
    } else {
        sht_stageA<<<dim3(6, MDIM), 256, 0, stream>>>(pct, xA, xs);
    }
    sht_stageB4<<<dim3(2 * MDIM), 512, 0, stream>>>(xs, Tp, out);
}

// Round 7
// 582.849 us; speedup vs baseline: 1.2465x; 1.0319x over previous
//
#include <hip/hip_runtime.h>
#include <cstddef>

#define CC   128
#define LDIM 361
#define MDIM 361
#define KDIM 361
#define NLON 720
#define LP   384          // padded l (stage A K-dim)
#define KP   384          // padded k rows for pctT
#define KTP  384          // xsT row stride (k-contiguous)
#define MRP  736          // padded mr (stage B K-dim)
#define NP   768          // padded n (stage B N-dim)
#define CK   (CC*KDIM)    // 46208
#define CR   (2*CC)       // 256

typedef __attribute__((ext_vector_type(8))) short short8;
typedef __attribute__((ext_vector_type(4))) float floatx4;

__device__ __forceinline__ unsigned short f2bf(float f) {
    union { float f; unsigned u; } v; v.f = f;
    unsigned u = v.u;
    u += 0x7fffu + ((u >> 16) & 1u);   // RNE
    return (unsigned short)(u >> 16);
}

__device__ __forceinline__ void async_copy16(const void* g, void* l) {
    __builtin_amdgcn_global_load_lds(
        (const __attribute__((address_space(1))) void*)g,
        (__attribute__((address_space(3))) void*)l, 16, 0, 0);
}

// Bijective XCD-chunk swizzle (m204).
__device__ __forceinline__ int xcd_swz(int id, int P) {
    int x = id & 7, g = id >> 3;
    int q = P >> 3, r = P & 7;
    int start = (x < r) ? x * (q + 1) : r * (q + 1) + (x - r) * q;
    return start + g;
}

// ---------------------------------------------------------------------------
// Tp[n][mr] bf16, n<720 & mr<722 real weights, else 0 (pad kills xs poison).
__global__ void sht_gen_T(unsigned short* __restrict__ Tp) {
    int idx = blockIdx.x * 256 + threadIdx.x;
    if (idx >= NP * MRP) return;
    int n = idx / MRP, mr = idx - n * MRP;
    float v = 0.f;
    if (n < NLON && mr < 2 * MDIM) {
        int m = mr >> 1, im = mr & 1;
        if (m == 0)            v = im ? 0.f : 1.f;
        else if (m == MDIM-1)  v = im ? 0.f : ((n & 1) ? -1.f : 1.f);
        else {
            int ph = (m * n) % NLON;
            float ang = (float)ph * (float)(3.14159265358979323846 / 360.0);
            v = im ? (-2.f * sinf(ang)) : (2.f * cosf(ang));
        }
    }
    Tp[idx] = f2bf(v);
}

// ---------------------------------------------------------------------------
// x fp32 [c][l][m][r] -> xA bf16 [m][cr=2c+r][LP]  (round-6 plane version)
__global__ __launch_bounds__(256)
void sht_prep_x(const float* __restrict__ x, unsigned short* __restrict__ xA) {
    __shared__ float tp[2][32 * 65 + 4];
    const int mt = blockIdx.x;         // 0..11
    const int lt = blockIdx.y;         // 0..5
    const int c  = blockIdx.z;         // 0..127
    const int t  = threadIdx.x;

    #pragma unroll
    for (int u = 0; u < 8; ++u) {
        int p  = t + 256 * u;
        int li = p >> 5, mi = p & 31;
        int l = lt * 64 + li, m = mt * 32 + mi;
        float2 v = make_float2(0.f, 0.f);
        if (l < LDIM && m < MDIM)
            v = *(const float2*)(x + ((size_t)(c * LDIM + l) * MDIM + m) * 2);
        tp[0][mi * 65 + li] = v.x;
        tp[1][mi * 65 + li] = v.y;
    }
    __syncthreads();

    #pragma unroll
    for (int u = 0; u < 2; ++u) {
        int s  = t + 256 * u;          // 0..511
        int mi = s >> 4, rr = (s >> 3) & 1, lo = (s & 7) * 8;
        int m = mt * 32 + mi;
        if (m >= MDIM) continue;
        const float* pl = &tp[rr][mi * 65];
        short8 h;
        #pragma unroll
        for (int e = 0; e < 8; ++e)
            h[e] = (short)f2bf(pl[lo + e]);
        *(short8*)(xA + ((size_t)m * CR + 2 * c + rr) * LP + lt * 64 + lo) = h;
    }
}

// ---------------------------------------------------------------------------
// pct fp32 [m][l][k] -> pctT bf16 [m][k][LP] v2: 64lx64k tiles (4x work/block
// vs round-1 32x32 version; that one was latency/launch-bound at 3.3 TB/s).
__global__ __launch_bounds__(256)
void sht_prep_pct(const float* __restrict__ pct, unsigned short* __restrict__ pctT) {
    __shared__ float tile[64][65];     // 16.6 KB
    const int m  = blockIdx.y;
    const int bx = blockIdx.x;         // 0..35
    const int kt = bx % 6, lt = bx / 6;
    const int l0 = lt * 64, k0 = kt * 64;
    const int t  = threadIdx.x;

    const int ki = t & 63, lb = t >> 6;    // 4 l-rows per pass
    #pragma unroll
    for (int u = 0; u < 16; ++u) {
        int li = lb + 4 * u;
        int l = l0 + li, k = k0 + ki;
        float v = 0.f;
        if (l < LDIM && k < KDIM)
            v = pct[((size_t)m * LDIM + l) * KDIM + k];
        tile[li][ki] = v;
    }
    __syncthreads();

    #pragma unroll
    for (int u = 0; u < 2; ++u) {
        int s = t + 256 * u;               // 0..511
        int ko = s >> 3, lo = (s & 7) * 8; // 64 k-rows x 8 l-octets
        short8 h;
        #pragma unroll
        for (int e = 0; e < 8; ++e)
            h[e] = (short)f2bf(tile[lo + e][ko]);
        *(short8*)(pctT + ((size_t)m * KP + k0 + ko) * LP + l0 + lo) = h;
    }
}

// ---------------------------------------------------------------------------
// Stage A6: per-m GEMM, 3-buffer ring + counted vmcnt + T2 XOR-swizzle.
// Swizzle (rule 21): source lq ^= (row&3); read quad ^= (row&3); LDS linear.
// Fixes the 8-way bank conflict of row-stride-64B ds_read_b128 -> 2-way.
__global__ __launch_bounds__(512)
void sht_stageA6(const unsigned short* __restrict__ pctT, const unsigned short* __restrict__ xA,
                 unsigned short* __restrict__ xsT) {
    __shared__ unsigned short As[3][128 * 32];   // 24 KB
    __shared__ unsigned short Bs[3][384 * 32];   // 72 KB

    const int p   = xcd_swz(blockIdx.x, 2 * MDIM);
    const int m   = p >> 1, ct = p & 1;
    const int c0  = ct * 128;
    const int t   = threadIdx.x;
    const int w   = t >> 6, L = t & 63;
    const int wr  = w & 1, wc = w >> 1;
    const int lane15 = L & 15, quad = L >> 4;
    const int arr = t >> 2, alq = (t & 3) ^ (arr & 3);   // pre-swizzled source slot

    const unsigned short* xAm = xA + (size_t)m * CR * LP;
    const unsigned short* pTm = pctT + (size_t)m * KP * LP;

    floatx4 acc[4][6] = {};

    auto stage = [&](int buf, int kb) {
        async_copy16(xAm + (size_t)(c0 + arr) * LP + kb + alq * 8,
                     &As[buf][(w * 64) * 8]);
        #pragma unroll
        for (int u = 0; u < 3; ++u) {
            int s = u * 512 + t;
            int rr = s >> 2, lq = (s & 3) ^ (rr & 3);
            async_copy16(pTm + (size_t)rr * LP + kb + lq * 8,
                         &Bs[buf][(u * 512 + w * 64) * 8]);
        }
    };

    const int NT = LP / 32;    // 12
    stage(0, 0);
    stage(1, 32);

    for (int it = 0; it < NT; ++it) {
        const int cb = it % 3;
        if (it + 1 < NT) { asm volatile("s_waitcnt vmcnt(4)" ::: "memory"); }
        else             { asm volatile("s_waitcnt vmcnt(0)" ::: "memory"); }
        __builtin_amdgcn_sched_barrier(0);
        __builtin_amdgcn_s_barrier();
        __builtin_amdgcn_sched_barrier(0);

        short8 af[4], bf[6];
        #pragma unroll
        for (int i = 0; i < 4; ++i) {
            int row = wr * 64 + i * 16 + lane15;
            af[i] = *(const short8*)&As[cb][(row * 4 + (quad ^ (row & 3))) * 8];
        }
        #pragma unroll
        for (int j = 0; j < 6; ++j) {
            int row = wc * 96 + j * 16 + lane15;
            bf[j] = *(const short8*)&Bs[cb][(row * 4 + (quad ^ (row & 3))) * 8];
        }
        __builtin_amdgcn_s_setprio(1);
        #pragma unroll
        for (int i = 0; i < 4; ++i)
            #pragma unroll
            for (int j = 0; j < 6; ++j)
                acc[i][j] = __builtin_amdgcn_mfma_f32_16x16x32_bf16(af[i], bf[j], acc[i][j], 0, 0, 0);
        __builtin_amdgcn_s_setprio(0);

        if (it + 2 < NT) stage((it + 2) % 3, (it + 2) * 32);
    }

    // coalesced: lane15 -> consecutive k; 16-lane group = 32B contiguous
    #pragma unroll
    for (int i = 0; i < 4; ++i) {
        #pragma unroll
        for (int j = 0; j < 6; ++j) {
            int k = wc * 96 + j * 16 + lane15;
            #pragma unroll
            for (int e = 0; e < 4; ++e) {
                int cr = c0 + wr * 64 + i * 16 + quad * 4 + e;
                xsT[((size_t)m * CR + cr) * KTP + k] = f2bf(acc[i][j][e]);
            }
        }
    }
}

// ---------------------------------------------------------------------------
// xsT bf16 [m][cr][KTP] -> xs bf16 [ck][MRP]; u32-pack transpose, <=2-way banks.
__global__ __launch_bounds__(256)
void sht_xs_tr(const unsigned short* __restrict__ xsT, unsigned short* __restrict__ xs) {
    __shared__ unsigned tile32[64 * 65];   // [k][mi] u32 = (bf16 r0 | r1<<16)
    const int c  = blockIdx.y;          // 0..127
    const int bx = blockIdx.x;          // 0..35
    const int mt = bx / 6, kt = bx % 6;
    const int m0 = mt * 64, k0 = kt * 64;
    const int t  = threadIdx.x;

    #pragma unroll
    for (int u = 0; u < 2; ++u) {
        int q  = t + 256 * u;
        int mi = q >> 3, ko8 = q & 7;
        int m  = m0 + mi;
        short8 a = {}, b = {};
        if (m < MDIM) {
            const unsigned short* base = xsT + ((size_t)m * CR + 2 * c) * KTP + k0 + ko8 * 8;
            a = *(const short8*)base;
            b = *(const short8*)(base + KTP);
        }
        #pragma unroll
        for (int e = 0; e < 8; ++e)
            tile32[(ko8 * 8 + e) * 65 + mi] =
                (unsigned)(unsigned short)a[e] | ((unsigned)(unsigned short)b[e] << 16);
    }
    __syncthreads();

    #pragma unroll
    for (int u = 0; u < 4; ++u) {
        int q  = t + 256 * u;
        int kk = q >> 4, mc = q & 15;
        int k  = k0 + kk;
        int mr0 = 2 * m0 + mc * 8;
        if (k >= KDIM || mr0 >= MRP) continue;
        unsigned w0 = tile32[kk * 65 + mc * 4 + 0];
        unsigned w1 = tile32[kk * 65 + mc * 4 + 1];
        unsigned w2 = tile32[kk * 65 + mc * 4 + 2];
        unsigned w3 = tile32[kk * 65 + mc * 4 + 3];
        unsigned* dst = (unsigned*)(xs + (size_t)(c * KDIM + k) * MRP + mr0);
        dst[0] = w0; dst[1] = w1; dst[2] = w2; dst[3] = w3;
    }
}

// ---------------------------------------------------------------------------
// Stage A2 (fast1 fallback): scatter epilogue direct to xs (round-3, 148us).
__global__ __launch_bounds__(512)
void sht_stageA2(const unsigned short* __restrict__ pctT, const unsigned short* __restrict__ xA,
                 unsigned short* __restrict__ xs) {
    __shared__ unsigned short As[128 * 32];
    __shared__ unsigned short Bs[384 * 32];

    const int p   = xcd_swz(blockIdx.x, 2 * MDIM);
    const int m   = p >> 1, ct = p & 1;
    const int c0  = ct * 128;
    const int t   = threadIdx.x;
    const int w   = t >> 6, L = t & 63;
    const int wr  = w & 1, wc = w >> 1;
    const int lane15 = L & 15, quad = L >> 4;
    const int arr = t >> 2, alq = t & 3;

    const unsigned short* xAm = xA + (size_t)m * CR * LP;
    const unsigned short* pTm = pctT + (size_t)m * KP * LP;

    floatx4 acc[4][6] = {};

    for (int kb = 0; kb < LP; kb += 32) {
        async_copy16(xAm + (size_t)(c0 + arr) * LP + kb + alq * 8,
                     As + (size_t)(w * 64) * 8);
        #pragma unroll
        for (int u = 0; u < 3; ++u) {
            int s = u * 512 + t;
            int rr = s >> 2, lq = s & 3;
            async_copy16(pTm + (size_t)rr * LP + kb + lq * 8,
                         Bs + (size_t)(u * 512 + w * 64) * 8);
        }
        __syncthreads();

        short8 af[4], bf[6];
        #pragma unroll
        for (int i = 0; i < 4; ++i)
            af[i] = *(const short8*)&As[((wr * 64 + i * 16 + lane15) * 4 + quad) * 8];
        #pragma unroll
        for (int j = 0; j < 6; ++j)
            bf[j] = *(const short8*)&Bs[((wc * 96 + j * 16 + lane15) * 4 + quad) * 8];
        #pragma unroll
        for (int i = 0; i < 4; ++i)
            #pragma unroll
            for (int j = 0; j < 6; ++j)
                acc[i][j] = __builtin_amdgcn_mfma_f32_16x16x32_bf16(af[i], bf[j], acc[i][j], 0, 0, 0);
        __syncthreads();
    }

    #pragma unroll
    for (int j = 0; j < 6; ++j) {
        int k = wc * 96 + j * 16 + lane15;
        if (k >= KDIM) continue;
        #pragma unroll
        for (int i = 0; i < 4; ++i) {
            #pragma unroll
            for (int eh = 0; eh < 2; ++eh) {
                int cr = c0 + wr * 64 + i * 16 + quad * 4 + eh * 2;
                int c  = cr >> 1;
                unsigned pack = (unsigned)f2bf(acc[i][j][eh * 2]) |
                                ((unsigned)f2bf(acc[i][j][eh * 2 + 1]) << 16);
                *(unsigned*)(xs + (size_t)(c * KDIM + k) * MRP + 2 * m) = pack;
            }
        }
    }
}

// ---------------------------------------------------------------------------
// Stage A (tier0 fallback): original in-loop fp32 pct staging.
__global__ __launch_bounds__(256)
void sht_stageA(const float* __restrict__ pct, const unsigned short* __restrict__ xA,
                unsigned short* __restrict__ xs) {
    __shared__ unsigned short As[128 * 32];
    __shared__ unsigned short Bs[32 * 130];

    const int m   = blockIdx.y;
    const int ct  = blockIdx.x & 1;
    const int kt  = blockIdx.x >> 1;
    const int c0  = ct * 128;
    const int n0  = kt * 128;
    const int t   = threadIdx.x;
    const int w   = t >> 6, L = t & 63;
    const int wr  = w & 1, wc = w >> 1;
    const int lane15 = L & 15, quad = L >> 4;
    const int bl = t >> 3, bkq = t & 7;

    const unsigned short* xAm = xA + (size_t)m * CR * LP;
    const float* pctm = pct + (size_t)m * LDIM * KDIM;

    floatx4 acc[4][4] = {};

    for (int kb = 0; kb < LP; kb += 32) {
        #pragma unroll
        for (int i = 0; i < 2; ++i) {
            int s = w * 128 + i * 64 + L;
            int cr = s >> 2, lq = s & 3;
            async_copy16(xAm + (size_t)(c0 + cr) * LP + kb + lq * 8,
                         As + (size_t)(w * 128 + i * 64) * 8);
        }
        {
            int l = kb + bl;
            bool lok = (l < LDIM);
            const float* prow = pctm + (size_t)l * KDIM;
            #pragma unroll
            for (int u = 0; u < 4; ++u) {
                int kc = n0 + u * 32 + bkq * 4;
                float f0 = (lok && kc + 0 < KDIM) ? prow[kc + 0] : 0.f;
                float f1 = (lok && kc + 1 < KDIM) ? prow[kc + 1] : 0.f;
                float f2 = (lok && kc + 2 < KDIM) ? prow[kc + 2] : 0.f;
                float f3 = (lok && kc + 3 < KDIM) ? prow[kc + 3] : 0.f;
                unsigned* bp = (unsigned*)&Bs[bl * 130 + u * 32 + bkq * 4];
                bp[0] = (unsigned)f2bf(f0) | ((unsigned)f2bf(f1) << 16);
                bp[1] = (unsigned)f2bf(f2) | ((unsigned)f2bf(f3) << 16);
            }
        }
        __syncthreads();

        short8 af[4];
        #pragma unroll
        for (int i = 0; i < 4; ++i) {
            int row = wr * 64 + i * 16 + lane15;
            af[i] = *(const short8*)&As[(row * 4 + quad) * 8];
        }
        #pragma unroll
        for (int jf = 0; jf < 4; ++jf) {
            int col = wc * 64 + jf * 16 + lane15;
            short8 bf;
            #pragma unroll
            for (int j = 0; j < 8; ++j)
                bf[j] = (short)Bs[(quad * 8 + j) * 130 + col];
            #pragma unroll
            for (int i = 0; i < 4; ++i)
                acc[i][jf] = __builtin_amdgcn_mfma_f32_16x16x32_bf16(af[i], bf, acc[i][jf], 0, 0, 0);
        }
        __syncthreads();
    }

    #pragma unroll
    for (int i = 0; i < 4; ++i) {
        #pragma unroll
        for (int jf = 0; jf < 4; ++jf) {
            int k = n0 + wc * 64 + jf * 16 + lane15;
            if (k >= KDIM) continue;
            #pragma unroll
            for (int eh = 0; eh < 2; ++eh) {
                int cr = c0 + wr * 64 + i * 16 + quad * 4 + eh * 2;
                int c  = cr >> 1;
                unsigned pack = (unsigned)f2bf(acc[i][jf][eh * 2]) |
                                ((unsigned)f2bf(acc[i][jf][eh * 2 + 1]) << 16);
                *(unsigned*)(xs + (size_t)(c * KDIM + k) * MRP + 2 * m) = pack;
            }
        }
    }
}

// ---------------------------------------------------------------------------
// Stage B5: out[ck][j] = sum_mr xs[ck][mr] * Tp[j][mr]
// 3-buffer ring + counted vmcnt + T2 XOR-swizzle (same scheme as A6).
__global__ __launch_bounds__(512)
void sht_stageB5(const unsigned short* __restrict__ xs, const unsigned short* __restrict__ Tp,
                 float* __restrict__ out) {
    __shared__ unsigned short As[3][128 * 32];   // 24 KB
    __shared__ unsigned short Bs[3][384 * 32];   // 72 KB

    const int p   = xcd_swz(blockIdx.x, 2 * MDIM);
    const int ckt = p >> 1, nt = p & 1;
    const int ck0 = ckt * 128, n0 = nt * 384;
    const int t   = threadIdx.x;
    const int w   = t >> 6, L = t & 63;
    const int wr  = w & 1, wc = w >> 1;
    const int lane15 = L & 15, quad = L >> 4;
    const int arr = t >> 2, alq = (t & 3) ^ (arr & 3);   // pre-swizzled source slot

    floatx4 acc[4][6] = {};

    auto stage = [&](int buf, int kb) {
        async_copy16(xs + (size_t)(ck0 + arr) * MRP + kb + alq * 8,
                     &As[buf][(w * 64) * 8]);
        #pragma unroll
        for (int u = 0; u < 3; ++u) {
            int s = u * 512 + t;
            int rr = s >> 2, lq = (s & 3) ^ (rr & 3);
            async_copy16(Tp + (size_t)(n0 + rr) * MRP + kb + lq * 8,
                         &Bs[buf][(u * 512 + w * 64) * 8]);
        }
    };

    const int NT = MRP / 32;   // 23
    stage(0, 0);
    stage(1, 32);

    for (int it = 0; it < NT; ++it) {
        const int cb = it % 3;
        if (it + 1 < NT) { asm volatile("s_waitcnt vmcnt(4)" ::: "memory"); }
        else             { asm volatile("s_waitcnt vmcnt(0)" ::: "memory"); }
        __builtin_amdgcn_sched_barrier(0);
        __builtin_amdgcn_s_barrier();
        __builtin_amdgcn_sched_barrier(0);

        short8 af[4], bf[6];
        #pragma unroll
        for (int i = 0; i < 4; ++i) {
            int row = wr * 64 + i * 16 + lane15;
            af[i] = *(const short8*)&As[cb][(row * 4 + (quad ^ (row & 3))) * 8];
        }
        #pragma unroll
        for (int j = 0; j < 6; ++j) {
            int row = wc * 96 + j * 16 + lane15;
            bf[j] = *(const short8*)&Bs[cb][(row * 4 + (quad ^ (row & 3))) * 8];
        }
        __builtin_amdgcn_s_setprio(1);
        #pragma unroll
        for (int i = 0; i < 4; ++i)
            #pragma unroll
            for (int j = 0; j < 6; ++j)
                acc[i][j] = __builtin_amdgcn_mfma_f32_16x16x32_bf16(af[i], bf[j], acc[i][j], 0, 0, 0);
        __builtin_amdgcn_s_setprio(0);

        if (it + 2 < NT) stage((it + 2) % 3, (it + 2) * 32);
    }

    #pragma unroll
    for (int i = 0; i < 4; ++i) {
        int ckr = ck0 + wr * 64 + i * 16 + quad * 4;
        #pragma unroll
        for (int j = 0; j < 6; ++j) {
            int jj = n0 + wc * 96 + j * 16 + lane15;
            if (jj >= NLON) continue;
            #pragma unroll
            for (int e = 0; e < 4; ++e)
                out[(size_t)(ckr + e) * NLON + jj] = acc[i][j][e];
        }
    }
}

// ---------------------------------------------------------------------------
extern "C" void kernel_launch(void* const* d_in, const int* in_sizes, int n_in,
                              void* d_out, int out_size, void* d_ws, size_t ws_size,
                              hipStream_t stream) {
    const float* x   = (const float*)d_in[0];   // [1,128,361,361,2] fp32
    const float* pct = (const float*)d_in[1];   // [361,361,361] fp32
    float* out = (float*)d_out;                 // [1,128,361,720] fp32

    unsigned short* xs = (unsigned short*)d_ws;              // CK*MRP (68.0 MB)
    unsigned short* Tp = xs + (size_t)CK * MRP;              // NP*MRP (1.13 MB)
    unsigned short* xA = (unsigned short*)d_out;             // dead before stage B

    const size_t base_shorts = (size_t)CK * MRP + (size_t)NP * MRP;
    const size_t pctT_shorts = (size_t)MDIM * KP * LP;       // 106.5 MB
    const size_t xsT_shorts  = (size_t)MDIM * CR * KTP;      // 71.0 MB
    const bool fast1 = ws_size >= (base_shorts + pctT_shorts) * sizeof(unsigned short);
    const bool fast2 = ws_size >= (base_shorts + pctT_shorts + xsT_shorts) * sizeof(unsigned short);

    sht_gen_T<<<(NP * MRP + 255) / 256, 256, 0, stream>>>(Tp);
    sht_prep_x<<<dim3(12, 6, 128), 256, 0, stream>>>(x, xA);
    if (fast2) {
        unsigned short* pctT = Tp + (size_t)NP * MRP;
        unsigned short* xsT  = pctT + pctT_shorts;
        sht_prep_pct<<<dim3(36, MDIM), 256, 0, stream>>>(pct, pctT);
        sht_stageA6<<<dim3(2 * MDIM), 512, 0, stream>>>(pctT, xA, xsT);
        sht_xs_tr<<<dim3(36, 128), 256, 0, stream>>>(xsT, xs);
    } else if (fast1) {
        unsigned short* pctT = Tp + (size_t)NP * MRP;
        sht_prep_pct<<<dim3(36, MDIM), 256, 0, stream>>>(pct, pctT);
        sht_stageA2<<<dim3(2 * MDIM), 512, 0, stream>>>(pctT, xA, xs);
    } else {
        sht_stageA<<<dim3(6, MDIM), 256, 0, stream>>>(pct, xA, xs);
    }
    sht_stageB5<<<dim3(2 * MDIM), 512, 0, stream>>>(xs, Tp, out);
}